// Round 8
// baseline (704.735 us; speedup 1.0000x reference)
//
#include <hip/hip_runtime.h>
#include <math.h>

// ---------------------------------------------------------------------------
// SMLadaformer block on MI355X. bf16 MFMA GEMMs, f32 elsewhere.
// B=8, N=1024, D=1024, H=16, DEPTH=64, MLP=4096. M = B*N = 8192.
// R4: conditioning matmuls K-split (was half of runtime).
// R6: big GEMMs -> 256-col tile, 8-wave, double-buffered counted-vmcnt
//     pipeline (T3/T4), XOR-swizzled LDS via pre-swizzled global src (T2),
//     setprio around MFMA (T5). QKV merged into one N=3072 GEMM.
// ---------------------------------------------------------------------------

typedef __attribute__((ext_vector_type(8))) short short8;
typedef __attribute__((ext_vector_type(4))) float f32x4;

#define DEVI __device__ __forceinline__

DEVI unsigned short f2bf(float f) {
  union { float f; unsigned int u; } c; c.f = f;
  unsigned int r = c.u + 0x7fffu + ((c.u >> 16) & 1u);
  return (unsigned short)(r >> 16);
}
DEVI float bf2f(unsigned short u) {
  union { unsigned int u; float f; } c; c.u = ((unsigned int)u) << 16;
  return c.f;
}

DEVI void async16(const void* g, void* l) {
  __builtin_amdgcn_global_load_lds((const __attribute__((address_space(1))) void*)g,
                                   (__attribute__((address_space(3))) void*)l, 16, 0, 0);
}

// ---- transpose f32 [R][C] -> bf16 [C][R] --------------------------------
__global__ void transpose_bf16_k(const float* __restrict__ in,
                                 unsigned short* __restrict__ out, int R, int C) {
  __shared__ float tile[32][33];
  const int c0 = blockIdx.x * 32, r0 = blockIdx.y * 32;
  const int tx = threadIdx.x, ty = threadIdx.y;  // 32 x 8
#pragma unroll
  for (int j = 0; j < 4; j++) {
    int r = r0 + ty + j * 8, c = c0 + tx;
    if (r < R && c < C) tile[ty + j * 8][tx] = in[(size_t)r * C + c];
  }
  __syncthreads();
#pragma unroll
  for (int j = 0; j < 4; j++) {
    int c = c0 + ty + j * 8, r = r0 + tx;  // out[c][r]
    if (c < C && r < R) out[(size_t)c * R + r] = f2bf(tile[tx][ty + j * 8]);
  }
}

// ---- pad qa_b (16) -> 128 ------------------------------------------------
__global__ void pad_bias_k(const float* __restrict__ qa_b, float* __restrict__ pad) {
  int t = threadIdx.x;
  pad[t] = (t < 16) ? qa_b[t] : 0.f;
}

// ---- concat wq_b|wk_b|wv_b -> [3072] ------------------------------------
__global__ void bias3_k(const float* __restrict__ b0, const float* __restrict__ b1,
                        const float* __restrict__ b2, float* __restrict__ out) {
  const int t = blockIdx.x * 256 + threadIdx.x;  // 3072
  out[t] = (t < 1024) ? b0[t] : (t < 2048 ? b1[t - 1024] : b2[t - 2048]);
}

// ---- zero the conditioning accumulators (re-poison-safe init) -----------
__global__ void zero_k(float4* __restrict__ p) {
  p[blockIdx.x * 256 + threadIdx.x] = float4{0.f, 0.f, 0.f, 0.f};
}

// ---- skinny GEMM partial: acc[8][1024] += X[8,kchunk] @ W[kchunk,jtile] --
template <int NMAT>
__global__ __launch_bounds__(256) void skinny_k(const float* __restrict__ X,
                                                const float* __restrict__ W0,
                                                const float* __restrict__ W1,
                                                float* __restrict__ acc0,
                                                float* __restrict__ acc1) {
  const int tid = threadIdx.x;
  const int jt = blockIdx.x, kc = blockIdx.y;
  const int jl = tid & 63, kg = tid >> 6;
  const int jcol = jt * 64 + jl;
  __shared__ float xs[8][64];
  for (int i = tid; i < 512; i += 256) {
    const int b = i >> 6, kk = i & 63;
    xs[b][kk] = X[b * 1024 + kc * 64 + kk];
  }
  __syncthreads();
  float a0[8], a1[8];
#pragma unroll
  for (int b = 0; b < 8; b++) { a0[b] = 0.f; a1[b] = 0.f; }
#pragma unroll
  for (int kk = 0; kk < 16; kk++) {
    const int k = kg * 16 + kk;
    const float w0 = W0[(size_t)(kc * 64 + k) * 1024 + jcol];
#pragma unroll
    for (int b = 0; b < 8; b++) a0[b] += xs[b][k] * w0;
    if (NMAT == 2) {
      const float w1 = W1[(size_t)(kc * 64 + k) * 1024 + jcol];
#pragma unroll
      for (int b = 0; b < 8; b++) a1[b] += xs[b][k] * w1;
    }
  }
  __shared__ float red[256][9];
#pragma unroll
  for (int b = 0; b < 8; b++) red[tid][b] = a0[b];
  __syncthreads();
  if (tid < 64) {
#pragma unroll
    for (int b = 0; b < 8; b++) {
      const float s = red[tid][b] + red[tid + 64][b] + red[tid + 128][b] + red[tid + 192][b];
      atomicAdd(&acc0[b * 1024 + jcol], s);
    }
  }
  if (NMAT == 2) {
    __syncthreads();
#pragma unroll
    for (int b = 0; b < 8; b++) red[tid][b] = a1[b];
    __syncthreads();
    if (tid < 64) {
#pragma unroll
      for (int b = 0; b < 8; b++) {
        const float s = red[tid][b] + red[tid + 64][b] + red[tid + 128][b] + red[tid + 192][b];
        atomicAdd(&acc1[b * 1024 + jcol], s);
      }
    }
  }
}

// ---- h = relu(acc + hb) --------------------------------------------------
__global__ void h_epi_k(const float* __restrict__ acc, const float* __restrict__ hb,
                        float* __restrict__ h) {
  const int i = blockIdx.x * 256 + threadIdx.x;
  h[i] = fmaxf(acc[i] + hb[i & 1023], 0.f);
}

// ---- LayerNorm(last dim) * (s_acc+gb)[row] + (t_acc+bb)[row] -> bf16 ----
__global__ __launch_bounds__(256) void ln_mod_k(const float* __restrict__ x,
                                                const float* __restrict__ s_acc,
                                                const float* __restrict__ t_acc,
                                                const float* __restrict__ gb,
                                                const float* __restrict__ bb,
                                                unsigned short* __restrict__ out) {
  const int lane = threadIdx.x & 63, wid = threadIdx.x >> 6;
  const size_t row = (size_t)blockIdx.x * 4 + wid;
  const int n = (int)(row & 1023);
  const float4* xr = (const float4*)(x + row * 1024);
  float4 v[4];
  float s = 0.f, ss = 0.f;
#pragma unroll
  for (int j = 0; j < 4; j++) {
    v[j] = xr[j * 64 + lane];
    s += v[j].x + v[j].y + v[j].z + v[j].w;
    ss += v[j].x * v[j].x + v[j].y * v[j].y + v[j].z * v[j].z + v[j].w * v[j].w;
  }
#pragma unroll
  for (int o = 32; o > 0; o >>= 1) { s += __shfl_xor(s, o); ss += __shfl_xor(ss, o); }
  const float mean = s * (1.f / 1024.f);
  const float var = ss * (1.f / 1024.f) - mean * mean;
  const float inv = rsqrtf(var + 1e-6f);
  const float scale = s_acc[row] + gb[n];
  const float shift = t_acc[row] + bb[n];
  const float sc = scale * inv;
  const float sh = shift - mean * sc;
#pragma unroll
  for (int j = 0; j < 4; j++) {
    ushort4 o4;
    o4.x = f2bf(v[j].x * sc + sh);
    o4.y = f2bf(v[j].y * sc + sh);
    o4.z = f2bf(v[j].z * sc + sh);
    o4.w = f2bf(v[j].w * sc + sh);
    *(ushort4*)(out + row * 1024 + (size_t)(j * 64 + lane) * 4) = o4;
  }
}

// ---------------------------------------------------------------------------
// 256-col-tile GEMM, 8 waves (2M x 4N), BK=64, 2-deep counted-vmcnt pipeline.
// LDS tiles XOR-swizzled (granule g ^= row&7): linear global_load_lds dest +
// inverse-swizzled GLOBAL source, swizzled ds_read (rule #21).
// EPI 0: QKV split (N=3072 -> 3 contiguous [M][1024] bf16 buffers)
// EPI 1: gelu(exact) -> bf16 stride N
// EPI 2: +resid -> f32 stride N
template <int EPI, int BM>
__global__ __launch_bounds__(512, 2) void gemm256(const unsigned short* __restrict__ A,
                                                  const unsigned short* __restrict__ BT,
                                                  const float* __restrict__ bias,
                                                  const float* __restrict__ resid,
                                                  void* __restrict__ Cout,
                                                  int M, int N, int K) {
  constexpr int WROWS = BM / 2;        // per-wave output rows
  constexpr int MF = WROWS / 16;       // m-fragments per wave
  constexpr int ALOADS = (BM * 8) / 512;
  constexpr int NLOADS = ALOADS + 4;   // gload_lds per thread per tile
  __shared__ unsigned short As[2][BM * 64];
  __shared__ unsigned short Bs[2][256 * 64];
  const int tid = threadIdx.x;
  const int lane = tid & 63, w = tid >> 6;
  const int wm = w >> 2, wn = w & 3;
  const int lr = lane & 15;
  const int g0 = lane >> 4;            // k-granule of this lane (0..3) per half
  const size_t brow = (size_t)blockIdx.y * BM;
  const size_t bcol = (size_t)blockIdx.x * 256;
  const unsigned short* Ab = A + brow * (size_t)K;
  const unsigned short* Bb = BT + bcol * (size_t)K;
  const int NT = K >> 6;

  const f32x4 zero = {0.f, 0.f, 0.f, 0.f};
  f32x4 acc[MF][4];
#pragma unroll
  for (int m = 0; m < MF; m++)
#pragma unroll
    for (int n = 0; n < 4; n++) acc[m][n] = zero;

  auto stage = [&](int k0, int d) {
#pragma unroll
    for (int i = 0; i < ALOADS; i++) {
      const int c = i * 512 + tid;
      const int r = c >> 3, g = c & 7;
      const int gl = g ^ (r & 7);      // inverse swizzle on global source
      async16(Ab + (size_t)r * K + (k0 + gl * 8), &As[d][c * 8]);
    }
#pragma unroll
    for (int i = 0; i < 4; i++) {
      const int c = i * 512 + tid;
      const int r = c >> 3, g = c & 7;
      const int gl = g ^ (r & 7);
      async16(Bb + (size_t)r * K + (k0 + gl * 8), &Bs[d][c * 8]);
    }
  };

  stage(0, 0);
  stage(64, 1);
  if constexpr (NLOADS == 8) asm volatile("s_waitcnt vmcnt(8)" ::: "memory");
  else asm volatile("s_waitcnt vmcnt(6)" ::: "memory");
  __builtin_amdgcn_s_barrier();

  for (int t = 0; t < NT; ++t) {
    const unsigned short* as = As[t & 1];
    const unsigned short* bs = Bs[t & 1];
#pragma unroll
    for (int kk = 0; kk < 64; kk += 32) {
      const int gk = (kk >> 3) + g0;   // logical granule of this lane's col
      short8 bfrag[4];
#pragma unroll
      for (int nf = 0; nf < 4; nf++) {
        const int r = wn * 64 + nf * 16 + lr;
        bfrag[nf] = *(const short8*)&bs[r * 64 + ((gk ^ (r & 7)) << 3)];
      }
      __builtin_amdgcn_s_setprio(1);
#pragma unroll
      for (int mf = 0; mf < MF; mf++) {
        const int r = wm * WROWS + mf * 16 + lr;
        const short8 afrag = *(const short8*)&as[r * 64 + ((gk ^ (r & 7)) << 3)];
#pragma unroll
        for (int nf = 0; nf < 4; nf++)
          acc[mf][nf] = __builtin_amdgcn_mfma_f32_16x16x32_bf16(afrag, bfrag[nf], acc[mf][nf], 0, 0, 0);
      }
      __builtin_amdgcn_s_setprio(0);
    }
    asm volatile("" ::: "memory");
    __builtin_amdgcn_s_barrier();      // all waves done reading buf (t&1)
    if (t + 2 < NT) {
      stage((t + 2) << 6, t & 1);      // prefetch 2 ahead into freed buf
      if constexpr (NLOADS == 8) asm volatile("s_waitcnt vmcnt(8)" ::: "memory");
      else asm volatile("s_waitcnt vmcnt(6)" ::: "memory");
    } else {
      asm volatile("s_waitcnt vmcnt(0)" ::: "memory");
    }
    __builtin_amdgcn_s_barrier();      // buf ((t+1)&1) now resident
  }

  const int lc = lane & 15, lrow = (lane >> 4) * 4;
#pragma unroll
  for (int nf = 0; nf < 4; nf++) {
    const size_t col = bcol + wn * 64 + nf * 16 + lc;
    const float bv = bias[col];
#pragma unroll
    for (int mf = 0; mf < MF; mf++) {
#pragma unroll
      for (int j = 0; j < 4; j++) {
        const size_t row = brow + wm * WROWS + mf * 16 + lrow + j;
        float v = acc[mf][nf][j] + bv;
        if (EPI == 0) {
          ((unsigned short*)Cout)[(size_t)(col >> 10) * ((size_t)M << 10) + row * 1024 + (col & 1023)] = f2bf(v);
        } else if (EPI == 1) {
          v = 0.5f * v * (1.0f + erff(v * 0.70710678118654752f));
          ((unsigned short*)Cout)[row * (size_t)N + col] = f2bf(v);
        } else {
          const size_t idx = row * (size_t)N + col;
          ((float*)Cout)[idx] = v + resid[idx];
        }
      }
    }
  }
}

// ---- 128x128 GEMM (kept for logits, N=128): +bias -> f32 ----------------
template <int EPI>
__global__ __launch_bounds__(256) void gemm_bf16(const unsigned short* __restrict__ A,
                                                 const unsigned short* __restrict__ BT,
                                                 const float* __restrict__ bias,
                                                 const float* __restrict__ resid,
                                                 void* __restrict__ Cout,
                                                 int M, int N, int K) {
  __shared__ unsigned short As[128 * 64];
  __shared__ unsigned short Bs[128 * 64];
  const int tid = threadIdx.x;
  const int lane = tid & 63, wid = tid >> 6;
  const int wr = wid >> 1, wc = wid & 1;
  const size_t brow = (size_t)blockIdx.y * 128;
  const size_t bcol = (size_t)blockIdx.x * 128;
  const unsigned short* Ab = A + brow * (size_t)K;
  const unsigned short* Bb = BT + bcol * (size_t)K;

  const f32x4 zero = {0.f, 0.f, 0.f, 0.f};
  f32x4 acc[4][4];
#pragma unroll
  for (int m = 0; m < 4; m++)
#pragma unroll
    for (int n = 0; n < 4; n++) acc[m][n] = zero;

  for (int k0 = 0; k0 < K; k0 += 64) {
#pragma unroll
    for (int i = 0; i < 4; i++) {
      const int eo = (i * 256 + tid) * 8;
      const int r = eo >> 6, c = eo & 63;
      async16(Ab + (size_t)r * K + (k0 + c), &As[eo]);
      async16(Bb + (size_t)r * K + (k0 + c), &Bs[eo]);
    }
    __syncthreads();
    const int lr = lane & 15, lk = (lane >> 4) * 8;
#pragma unroll
    for (int kk = 0; kk < 64; kk += 32) {
      short8 af[4], bfv[4];
#pragma unroll
      for (int m = 0; m < 4; m++)
        af[m] = *(const short8*)&As[(wr * 64 + m * 16 + lr) * 64 + kk + lk];
#pragma unroll
      for (int n = 0; n < 4; n++)
        bfv[n] = *(const short8*)&Bs[(wc * 64 + n * 16 + lr) * 64 + kk + lk];
#pragma unroll
      for (int m = 0; m < 4; m++)
#pragma unroll
        for (int n = 0; n < 4; n++)
          acc[m][n] = __builtin_amdgcn_mfma_f32_16x16x32_bf16(af[m], bfv[n], acc[m][n], 0, 0, 0);
    }
    __syncthreads();
  }

  const int lc = lane & 15, lr4 = (lane >> 4) * 4;
#pragma unroll
  for (int n = 0; n < 4; n++) {
    const size_t col = bcol + wc * 64 + n * 16 + lc;
    const float bv = bias[col];
#pragma unroll
    for (int m = 0; m < 4; m++) {
#pragma unroll
      for (int j = 0; j < 4; j++) {
        const size_t row = brow + wr * 64 + m * 16 + lr4 + j;
        const size_t idx = row * (size_t)N + col;
        ((float*)Cout)[idx] = acc[m][n][j] + bv;
      }
    }
  }
}

// ---- softmax over N for each (b,h); logits [M][128] f32, attn [B*H][N] --
__global__ __launch_bounds__(256) void softmax_k(const float* __restrict__ logits,
                                                 float* __restrict__ attn) {
  const int tid = threadIdx.x;
  const int bh = blockIdx.x;
  const int b = bh >> 4, h = bh & 15;
  __shared__ float redm[4];
  __shared__ float reds[4];
  float vals[4];
#pragma unroll
  for (int j = 0; j < 4; j++) {
    const int n = j * 256 + tid;
    vals[j] = logits[((size_t)b * 1024 + n) * 128 + h] * 0.125f;
  }
  float m = fmaxf(fmaxf(vals[0], vals[1]), fmaxf(vals[2], vals[3]));
#pragma unroll
  for (int o = 32; o > 0; o >>= 1) m = fmaxf(m, __shfl_xor(m, o));
  if ((tid & 63) == 0) redm[tid >> 6] = m;
  __syncthreads();
  m = fmaxf(fmaxf(redm[0], redm[1]), fmaxf(redm[2], redm[3]));
  float e[4];
  float s = 0.f;
#pragma unroll
  for (int j = 0; j < 4; j++) { e[j] = expf(vals[j] - m); s += e[j]; }
#pragma unroll
  for (int o = 32; o > 0; o >>= 1) s += __shfl_xor(s, o);
  if ((tid & 63) == 0) reds[tid >> 6] = s;
  __syncthreads();
  s = reds[0] + reds[1] + reds[2] + reds[3];
  const float invs = 1.f / s;
#pragma unroll
  for (int j = 0; j < 4; j++)
    attn[(size_t)bh * 1024 + j * 256 + tid] = e[j] * invs;
}

// ---- global_q[b,h,d] = sum_n attn[b,h,n] * Q[b,n,h*64+d] ----------------
__global__ __launch_bounds__(256) void global_q_k(const float* __restrict__ attn,
                                                  const unsigned short* __restrict__ Q,
                                                  float* __restrict__ gq) {
  const int tid = threadIdx.x;
  const int bh = blockIdx.x;
  const int b = bh >> 4, h = bh & 15;
  const int d = tid & 63, g = tid >> 6;
  const float* arow = attn + (size_t)bh * 1024;
  const unsigned short* qcol = Q + (size_t)b * 1024 * 1024 + h * 64 + d;
  float acc = 0.f;
  for (int n = g * 256; n < g * 256 + 256; n++)
    acc += arow[n] * bf2f(qcol[(size_t)n * 1024]);
  __shared__ float red[256];
  red[tid] = acc;
  __syncthreads();
  if (g == 0) gq[(size_t)bh * 64 + d] = red[d] + red[64 + d] + red[128 + d] + red[192 + d];
}

// ---- r = gq[b,h,d] * K * V (elementwise, bf16, in-place over K) ---------
__global__ __launch_bounds__(256) void r_k(const unsigned short* __restrict__ Kb,
                                           const unsigned short* __restrict__ Vb,
                                           const float* __restrict__ gq,
                                           unsigned short* __restrict__ R) {
  const size_t i = ((size_t)blockIdx.x * 256 + threadIdx.x) * 8;
  const int col = (int)(i & 1023);
  const size_t b = i >> 20;
  const int h = col >> 6, dd = col & 63;
  const float* g = gq + ((b << 4) + h) * 64 + dd;
  short8 kv = *(const short8*)(Kb + i);
  short8 vv = *(const short8*)(Vb + i);
  short8 r;
#pragma unroll
  for (int j = 0; j < 8; j++) {
    float f = g[j] * bf2f((unsigned short)kv[j]) * bf2f((unsigned short)vv[j]);
    r[j] = (short)f2bf(f);
  }
  *(short8*)(R + i) = r;
}

// ---------------------------------------------------------------------------
extern "C" void kernel_launch(void* const* d_in, const int* in_sizes, int n_in,
                              void* d_out, int out_size, void* d_ws, size_t ws_size,
                              hipStream_t stream) {
  (void)in_sizes; (void)n_in; (void)out_size; (void)ws_size;
  const float* inputs = (const float*)d_in[0];
  const float* z      = (const float*)d_in[1];
  const float* n1_hw = (const float*)d_in[2];  const float* n1_hb = (const float*)d_in[3];
  const float* n1_gw = (const float*)d_in[4];  const float* n1_gb = (const float*)d_in[5];
  const float* n1_bw = (const float*)d_in[6];  const float* n1_bb = (const float*)d_in[7];
  const float* wq_w  = (const float*)d_in[8];  const float* wq_b  = (const float*)d_in[9];
  const float* wk_w  = (const float*)d_in[10]; const float* wk_b  = (const float*)d_in[11];
  const float* wv_w  = (const float*)d_in[12]; const float* wv_b  = (const float*)d_in[13];
  const float* qa_w  = (const float*)d_in[14]; const float* qa_b  = (const float*)d_in[15];
  const float* out_w = (const float*)d_in[16]; const float* out_b = (const float*)d_in[17];
  const float* n2_hw = (const float*)d_in[18]; const float* n2_hb = (const float*)d_in[19];
  const float* n2_gw = (const float*)d_in[20]; const float* n2_gb = (const float*)d_in[21];
  const float* n2_bw = (const float*)d_in[22]; const float* n2_bb = (const float*)d_in[23];
  const float* mlp_w1 = (const float*)d_in[24]; const float* mlp_b1 = (const float*)d_in[25];
  const float* mlp_w2 = (const float*)d_in[26]; const float* mlp_b2 = (const float*)d_in[27];

  const int M = 8192, D = 1024, MLPD = 4096;

  char* ws = (char*)d_ws;
  size_t o = 0;
  auto alloc = [&](size_t bytes) -> char* {
    char* p = ws + o;
    o += (bytes + 255) & ~(size_t)255;
    return p;
  };
  unsigned short* wqkvT = (unsigned short*)alloc((size_t)3 * D * D * 2);  // [3072][1024]
  unsigned short* woT = (unsigned short*)alloc((size_t)D * D * 2);
  unsigned short* w1T = (unsigned short*)alloc((size_t)MLPD * D * 2);
  unsigned short* w2T = (unsigned short*)alloc((size_t)D * MLPD * 2);
  unsigned short* qaT = (unsigned short*)alloc((size_t)128 * D * 2);
  unsigned short* xn  = (unsigned short*)alloc((size_t)M * D * 2);
  char* big = alloc((size_t)M * MLPD * 2);  // 64MB: Q/K/V/logits early, hbuf late
  unsigned short* Qb = (unsigned short*)big;
  unsigned short* Kb = (unsigned short*)(big + (size_t)M * D * 2);
  unsigned short* Vb = (unsigned short*)(big + (size_t)M * D * 4);
  float* logits      = (float*)(big + (size_t)M * D * 6);  // [M][128] f32
  unsigned short* hbuf = (unsigned short*)big;             // [M][4096] bf16
  float* cacc  = (float*)alloc(6 * 8192 * 4);
  float* accH1 = cacc;
  float* accS1 = cacc + 1 * 8192;
  float* accT1 = cacc + 2 * 8192;
  float* accH2 = cacc + 3 * 8192;
  float* accS2 = cacc + 4 * 8192;
  float* accT2 = cacc + 5 * 8192;
  float* h1     = (float*)alloc(8 * 1024 * 4);
  float* h2     = (float*)alloc(8 * 1024 * 4);
  float* gq     = (float*)alloc(8 * 16 * 64 * 4);
  float* qa_b_pad = (float*)alloc(128 * 4);
  float* qkvb    = (float*)alloc(3072 * 4);

  float* out0 = (float*)d_out;                    // [M][D] final output / attn_out
  float* attn = (float*)d_out + (size_t)M * D;    // [B*H][N] attention maps

  const dim3 tb(32, 8);
  // weight transposes -> bf16 [N][K]; QKV concatenated into one [3072][1024]
  hipLaunchKernelGGL(transpose_bf16_k, dim3(32, 32), tb, 0, stream, wq_w, wqkvT, D, D);
  hipLaunchKernelGGL(transpose_bf16_k, dim3(32, 32), tb, 0, stream, wk_w, wqkvT + (size_t)D * D, D, D);
  hipLaunchKernelGGL(transpose_bf16_k, dim3(32, 32), tb, 0, stream, wv_w, wqkvT + (size_t)2 * D * D, D, D);
  hipLaunchKernelGGL(transpose_bf16_k, dim3(32, 32), tb, 0, stream, out_w, woT, D, D);
  hipLaunchKernelGGL(transpose_bf16_k, dim3(128, 32), tb, 0, stream, mlp_w1, w1T, D, MLPD);
  hipLaunchKernelGGL(transpose_bf16_k, dim3(32, 128), tb, 0, stream, mlp_w2, w2T, MLPD, D);
  hipLaunchKernelGGL(transpose_bf16_k, dim3(1, 32), tb, 0, stream, qa_w, qaT, D, 16);
  hipLaunchKernelGGL(pad_bias_k, dim3(1), dim3(128), 0, stream, qa_b, qa_b_pad);
  hipLaunchKernelGGL(bias3_k, dim3(12), dim3(256), 0, stream, wq_b, wk_b, wv_b, qkvb);

  // conditioning: zero accs, then K-split skinny GEMMs + epilogues
  hipLaunchKernelGGL(zero_k, dim3(48), dim3(256), 0, stream, (float4*)cacc);
  hipLaunchKernelGGL(skinny_k<1>, dim3(16, 16), dim3(256), 0, stream, z, n1_hw, (const float*)nullptr, accH1, (float*)nullptr);
  hipLaunchKernelGGL(h_epi_k, dim3(32), dim3(256), 0, stream, accH1, n1_hb, h1);
  hipLaunchKernelGGL(skinny_k<2>, dim3(16, 16), dim3(256), 0, stream, h1, n1_gw, n1_bw, accS1, accT1);
  hipLaunchKernelGGL(skinny_k<1>, dim3(16, 16), dim3(256), 0, stream, z, n2_hw, (const float*)nullptr, accH2, (float*)nullptr);
  hipLaunchKernelGGL(h_epi_k, dim3(32), dim3(256), 0, stream, accH2, n2_hb, h2);
  hipLaunchKernelGGL(skinny_k<2>, dim3(16, 16), dim3(256), 0, stream, h2, n2_gw, n2_bw, accS2, accT2);

  // LN1 -> xn (bf16)
  hipLaunchKernelGGL(ln_mod_k, dim3(M / 4), dim3(256), 0, stream, inputs, accS1, accT1, n1_gb, n1_bb, xn);

  // Q|K|V = xn @ wqkv (one N=3072 GEMM, epilogue splits into Qb/Kb/Vb)
  hipLaunchKernelGGL((gemm256<0, 256>), dim3(12, 32), dim3(512), 0, stream, xn, wqkvT, qkvb, (const float*)nullptr, (void*)Qb, M, 3072, D);

  // logits = Q @ qa_w + qa_b (padded to N=128)
  hipLaunchKernelGGL(gemm_bf16<3>, dim3(1, 64), dim3(256), 0, stream, Qb, qaT, qa_b_pad, (const float*)nullptr, (void*)logits, M, 128, D);

  // softmax -> attn maps (d_out region 1)
  hipLaunchKernelGGL(softmax_k, dim3(128), dim3(256), 0, stream, logits, attn);

  // global_q
  hipLaunchKernelGGL(global_q_k, dim3(128), dim3(256), 0, stream, attn, Qb, gq);

  // r = gq * K * V (in-place over K buffer)
  hipLaunchKernelGGL(r_k, dim3(M * D / 8 / 256), dim3(256), 0, stream, Kb, Vb, gq, Kb);

  // attn_out = inputs + r @ out_w + out_b  -> d_out region 0 (f32)
  hipLaunchKernelGGL((gemm256<2, 128>), dim3(4, 64), dim3(512), 0, stream, Kb, woT, out_b, inputs, (void*)out0, M, D, D);

  // LN2 -> xn (bf16)
  hipLaunchKernelGGL(ln_mod_k, dim3(M / 4), dim3(256), 0, stream, out0, accS2, accT2, n2_gb, n2_bb, xn);

  // MLP1 + exact gelu -> hbuf (bf16)
  hipLaunchKernelGGL((gemm256<1, 256>), dim3(16, 32), dim3(512), 0, stream, xn, w1T, mlp_b1, (const float*)nullptr, (void*)hbuf, M, MLPD, D);

  // MLP2 + attn_out residual -> final output (f32, in-place RMW on d_out)
  hipLaunchKernelGGL((gemm256<2, 128>), dim3(4, 64), dim3(512), 0, stream, hbuf, w2T, mlp_b2, out0, (void*)out0, M, D, MLPD);
}

// Round 9
// 667.655 us; speedup vs baseline: 1.0555x; 1.0555x over previous
//
#include <hip/hip_runtime.h>
#include <math.h>

// ---------------------------------------------------------------------------
// SMLadaformer block on MI355X. bf16 MFMA GEMMs, f32 elsewhere.
// B=8, N=1024, D=1024, H=16, DEPTH=64, MLP=4096. M = B*N = 8192.
// R4: conditioning matmuls K-split (was half of runtime).
// R6: 256-col tile, 8-wave, dbuf counted-vmcnt pipeline + LDS swizzle.
// R8: bf16 epilogues were 32B-segment scatter stores -> WRITE_SIZE 2.4x
//     (153MB for 64MB output, RMW fetches). Fix: swapped-operand MFMA
//     (lane holds 4 consecutive cols) + LDS-staged coalesced short8 stores.
//     Plus XCD-aware block swizzle (HBM-bound regime).
// ---------------------------------------------------------------------------

typedef __attribute__((ext_vector_type(8))) short short8;
typedef __attribute__((ext_vector_type(4))) float f32x4;

#define DEVI __device__ __forceinline__

DEVI unsigned short f2bf(float f) {
  union { float f; unsigned int u; } c; c.f = f;
  unsigned int r = c.u + 0x7fffu + ((c.u >> 16) & 1u);
  return (unsigned short)(r >> 16);
}
DEVI float bf2f(unsigned short u) {
  union { unsigned int u; float f; } c; c.u = ((unsigned int)u) << 16;
  return c.f;
}

DEVI void async16(const void* g, void* l) {
  __builtin_amdgcn_global_load_lds((const __attribute__((address_space(1))) void*)g,
                                   (__attribute__((address_space(3))) void*)l, 16, 0, 0);
}

// ---- transpose f32 [R][C] -> bf16 [C][R] --------------------------------
__global__ void transpose_bf16_k(const float* __restrict__ in,
                                 unsigned short* __restrict__ out, int R, int C) {
  __shared__ float tile[32][33];
  const int c0 = blockIdx.x * 32, r0 = blockIdx.y * 32;
  const int tx = threadIdx.x, ty = threadIdx.y;  // 32 x 8
#pragma unroll
  for (int j = 0; j < 4; j++) {
    int r = r0 + ty + j * 8, c = c0 + tx;
    if (r < R && c < C) tile[ty + j * 8][tx] = in[(size_t)r * C + c];
  }
  __syncthreads();
#pragma unroll
  for (int j = 0; j < 4; j++) {
    int c = c0 + ty + j * 8, r = r0 + tx;  // out[c][r]
    if (c < C && r < R) out[(size_t)c * R + r] = f2bf(tile[tx][ty + j * 8]);
  }
}

// ---- pad qa_b (16) -> 128 ------------------------------------------------
__global__ void pad_bias_k(const float* __restrict__ qa_b, float* __restrict__ pad) {
  int t = threadIdx.x;
  pad[t] = (t < 16) ? qa_b[t] : 0.f;
}

// ---- concat wq_b|wk_b|wv_b -> [3072] ------------------------------------
__global__ void bias3_k(const float* __restrict__ b0, const float* __restrict__ b1,
                        const float* __restrict__ b2, float* __restrict__ out) {
  const int t = blockIdx.x * 256 + threadIdx.x;  // 3072
  out[t] = (t < 1024) ? b0[t] : (t < 2048 ? b1[t - 1024] : b2[t - 2048]);
}

// ---- zero the conditioning accumulators (re-poison-safe init) -----------
__global__ void zero_k(float4* __restrict__ p) {
  p[blockIdx.x * 256 + threadIdx.x] = float4{0.f, 0.f, 0.f, 0.f};
}

// ---- skinny GEMM partial: acc[8][1024] += X[8,kchunk] @ W[kchunk,jtile] --
template <int NMAT>
__global__ __launch_bounds__(256) void skinny_k(const float* __restrict__ X,
                                                const float* __restrict__ W0,
                                                const float* __restrict__ W1,
                                                float* __restrict__ acc0,
                                                float* __restrict__ acc1) {
  const int tid = threadIdx.x;
  const int jt = blockIdx.x, kc = blockIdx.y;
  const int jl = tid & 63, kg = tid >> 6;
  const int jcol = jt * 64 + jl;
  __shared__ float xs[8][64];
  for (int i = tid; i < 512; i += 256) {
    const int b = i >> 6, kk = i & 63;
    xs[b][kk] = X[b * 1024 + kc * 64 + kk];
  }
  __syncthreads();
  float a0[8], a1[8];
#pragma unroll
  for (int b = 0; b < 8; b++) { a0[b] = 0.f; a1[b] = 0.f; }
#pragma unroll
  for (int kk = 0; kk < 16; kk++) {
    const int k = kg * 16 + kk;
    const float w0 = W0[(size_t)(kc * 64 + k) * 1024 + jcol];
#pragma unroll
    for (int b = 0; b < 8; b++) a0[b] += xs[b][k] * w0;
    if (NMAT == 2) {
      const float w1 = W1[(size_t)(kc * 64 + k) * 1024 + jcol];
#pragma unroll
      for (int b = 0; b < 8; b++) a1[b] += xs[b][k] * w1;
    }
  }
  __shared__ float red[256][9];
#pragma unroll
  for (int b = 0; b < 8; b++) red[tid][b] = a0[b];
  __syncthreads();
  if (tid < 64) {
#pragma unroll
    for (int b = 0; b < 8; b++) {
      const float s = red[tid][b] + red[tid + 64][b] + red[tid + 128][b] + red[tid + 192][b];
      atomicAdd(&acc0[b * 1024 + jcol], s);
    }
  }
  if (NMAT == 2) {
    __syncthreads();
#pragma unroll
    for (int b = 0; b < 8; b++) red[tid][b] = a1[b];
    __syncthreads();
    if (tid < 64) {
#pragma unroll
      for (int b = 0; b < 8; b++) {
        const float s = red[tid][b] + red[tid + 64][b] + red[tid + 128][b] + red[tid + 192][b];
        atomicAdd(&acc1[b * 1024 + jcol], s);
      }
    }
  }
}

// ---- h = relu(acc + hb) --------------------------------------------------
__global__ void h_epi_k(const float* __restrict__ acc, const float* __restrict__ hb,
                        float* __restrict__ h) {
  const int i = blockIdx.x * 256 + threadIdx.x;
  h[i] = fmaxf(acc[i] + hb[i & 1023], 0.f);
}

// ---- LayerNorm(last dim) * (s_acc+gb)[row] + (t_acc+bb)[row] -> bf16 ----
__global__ __launch_bounds__(256) void ln_mod_k(const float* __restrict__ x,
                                                const float* __restrict__ s_acc,
                                                const float* __restrict__ t_acc,
                                                const float* __restrict__ gb,
                                                const float* __restrict__ bb,
                                                unsigned short* __restrict__ out) {
  const int lane = threadIdx.x & 63, wid = threadIdx.x >> 6;
  const size_t row = (size_t)blockIdx.x * 4 + wid;
  const int n = (int)(row & 1023);
  const float4* xr = (const float4*)(x + row * 1024);
  float4 v[4];
  float s = 0.f, ss = 0.f;
#pragma unroll
  for (int j = 0; j < 4; j++) {
    v[j] = xr[j * 64 + lane];
    s += v[j].x + v[j].y + v[j].z + v[j].w;
    ss += v[j].x * v[j].x + v[j].y * v[j].y + v[j].z * v[j].z + v[j].w * v[j].w;
  }
#pragma unroll
  for (int o = 32; o > 0; o >>= 1) { s += __shfl_xor(s, o); ss += __shfl_xor(ss, o); }
  const float mean = s * (1.f / 1024.f);
  const float var = ss * (1.f / 1024.f) - mean * mean;
  const float inv = rsqrtf(var + 1e-6f);
  const float scale = s_acc[row] + gb[n];
  const float shift = t_acc[row] + bb[n];
  const float sc = scale * inv;
  const float sh = shift - mean * sc;
#pragma unroll
  for (int j = 0; j < 4; j++) {
    ushort4 o4;
    o4.x = f2bf(v[j].x * sc + sh);
    o4.y = f2bf(v[j].y * sc + sh);
    o4.z = f2bf(v[j].z * sc + sh);
    o4.w = f2bf(v[j].w * sc + sh);
    *(ushort4*)(out + row * 1024 + (size_t)(j * 64 + lane) * 4) = o4;
  }
}

// ---------------------------------------------------------------------------
// 256-col-tile GEMM, 8 waves (2M x 4N), BK=64, 2-deep counted-vmcnt pipeline,
// XCD-swizzled block ids. EPI 0/1 (bf16 out): swapped-operand MFMA (lane owns
// 4 consecutive cols) + LDS-staged fully-coalesced short8 stores.
// EPI 0: QKV split (N=3072 -> 3 contiguous [M][1024] bf16 buffers)
// EPI 1: gelu(exact) -> bf16 stride N
// EPI 2: +resid -> f32 stride N (64B segments, already clean)
template <int EPI, int BM>
__global__ __launch_bounds__(512, 2) void gemm256(const unsigned short* __restrict__ A,
                                                  const unsigned short* __restrict__ BT,
                                                  const float* __restrict__ bias,
                                                  const float* __restrict__ resid,
                                                  void* __restrict__ Cout,
                                                  int M, int N, int K) {
  constexpr bool SWAP = (EPI == 0 || EPI == 1);
  constexpr int WROWS = BM / 2;        // per-wave output rows
  constexpr int MF = WROWS / 16;       // m-fragments per wave
  constexpr int ALOADS = (BM * 8) / 512;
  constexpr int NLOADS = ALOADS + 4;   // gload_lds per thread per tile
  __shared__ unsigned short lds[2 * BM * 64 + 2 * 256 * 64];
  unsigned short* As0 = lds;                       // [2][BM*64]
  unsigned short* Bs0 = lds + 2 * BM * 64;         // [2][256*64]
  const int tid = threadIdx.x;
  const int lane = tid & 63, w = tid >> 6;
  const int wm = w >> 2, wn = w & 3;
  const int lr = lane & 15;
  const int g0 = lane >> 4;            // k-granule of this lane (0..3) per half
  // XCD-aware bijective swizzle (all grids have nwg % 8 == 0)
  const int nwg = gridDim.x * gridDim.y;
  const int rb = blockIdx.y * gridDim.x + blockIdx.x;
  const int sb = (rb & 7) * (nwg >> 3) + (rb >> 3);
  const size_t brow = (size_t)(sb / gridDim.x) * BM;
  const size_t bcol = (size_t)(sb % gridDim.x) * 256;
  const unsigned short* Ab = A + brow * (size_t)K;
  const unsigned short* Bb = BT + bcol * (size_t)K;
  const int NT = K >> 6;

  const f32x4 zero = {0.f, 0.f, 0.f, 0.f};
  f32x4 acc[MF][4];
#pragma unroll
  for (int m = 0; m < MF; m++)
#pragma unroll
    for (int n = 0; n < 4; n++) acc[m][n] = zero;

  auto stage = [&](int k0, int d) {
#pragma unroll
    for (int i = 0; i < ALOADS; i++) {
      const int c = i * 512 + tid;
      const int r = c >> 3, g = c & 7;
      const int gl = g ^ (r & 7);      // inverse swizzle on global source
      async16(Ab + (size_t)r * K + (k0 + gl * 8), &As0[(size_t)d * BM * 64 + c * 8]);
    }
#pragma unroll
    for (int i = 0; i < 4; i++) {
      const int c = i * 512 + tid;
      const int r = c >> 3, g = c & 7;
      const int gl = g ^ (r & 7);
      async16(Bb + (size_t)r * K + (k0 + gl * 8), &Bs0[(size_t)d * 256 * 64 + c * 8]);
    }
  };

  stage(0, 0);
  stage(64, 1);
  if constexpr (NLOADS == 8) asm volatile("s_waitcnt vmcnt(8)" ::: "memory");
  else asm volatile("s_waitcnt vmcnt(6)" ::: "memory");
  __builtin_amdgcn_s_barrier();

  for (int t = 0; t < NT; ++t) {
    const unsigned short* as = As0 + (size_t)(t & 1) * BM * 64;
    const unsigned short* bs = Bs0 + (size_t)(t & 1) * 256 * 64;
#pragma unroll
    for (int kk = 0; kk < 64; kk += 32) {
      const int gk = (kk >> 3) + g0;   // logical granule of this lane's col
      short8 bfrag[4];
#pragma unroll
      for (int nf = 0; nf < 4; nf++) {
        const int r = wn * 64 + nf * 16 + lr;
        bfrag[nf] = *(const short8*)&bs[r * 64 + ((gk ^ (r & 7)) << 3)];
      }
      __builtin_amdgcn_s_setprio(1);
#pragma unroll
      for (int mf = 0; mf < MF; mf++) {
        const int r = wm * WROWS + mf * 16 + lr;
        const short8 afrag = *(const short8*)&as[r * 64 + ((gk ^ (r & 7)) << 3)];
#pragma unroll
        for (int nf = 0; nf < 4; nf++) {
          if constexpr (SWAP)
            acc[mf][nf] = __builtin_amdgcn_mfma_f32_16x16x32_bf16(bfrag[nf], afrag, acc[mf][nf], 0, 0, 0);
          else
            acc[mf][nf] = __builtin_amdgcn_mfma_f32_16x16x32_bf16(afrag, bfrag[nf], acc[mf][nf], 0, 0, 0);
        }
      }
      __builtin_amdgcn_s_setprio(0);
    }
    asm volatile("" ::: "memory");
    __builtin_amdgcn_s_barrier();      // all waves done reading buf (t&1)
    if (t + 2 < NT) {
      stage((t + 2) << 6, t & 1);      // prefetch 2 ahead into freed buf
      if constexpr (NLOADS == 8) asm volatile("s_waitcnt vmcnt(8)" ::: "memory");
      else asm volatile("s_waitcnt vmcnt(6)" ::: "memory");
    } else {
      asm volatile("s_waitcnt vmcnt(0)" ::: "memory");
    }
    __builtin_amdgcn_s_barrier();      // buf ((t+1)&1) now resident
  }

  if constexpr (SWAP) {
    // acc is C^T-fragment: row = ...+lr, cols = ...+(lane>>4)*4+{0..3}.
    // Stage bf16 C tile [BM][256] in LDS (XOR bits 4-6 by row&7), then
    // stream out fully coalesced (512B contiguous per 32 lanes).
    unsigned short* cst = lds;  // BM*256 u16 <= 2*BM*64 + 2*256*64 u16
    const int g4 = (lane >> 4) * 4;
#pragma unroll
    for (int nf = 0; nf < 4; nf++) {
#pragma unroll
      for (int mf = 0; mf < MF; mf++) {
        const int row = wm * WROWS + mf * 16 + lr;
        const int colb = wn * 64 + nf * 16 + g4;
        const float4 bv = *(const float4*)&bias[bcol + colb];
        float v[4];
#pragma unroll
        for (int j = 0; j < 4; j++) {
          v[j] = acc[mf][nf][j] + (&bv.x)[j];
          if (EPI == 1) v[j] = 0.5f * v[j] * (1.0f + erff(v[j] * 0.70710678118654752f));
        }
        ushort4 p;
        p.x = f2bf(v[0]); p.y = f2bf(v[1]); p.z = f2bf(v[2]); p.w = f2bf(v[3]);
        const int byo = row * 512 + ((colb * 2) ^ ((row & 7) << 4));
        *(ushort4*)((char*)cst + byo) = p;
      }
    }
    __syncthreads();
    unsigned short* outp;
    size_t ostride;
    if (EPI == 0) {
      outp = (unsigned short*)Cout + (size_t)(bcol >> 10) * ((size_t)M << 10) + (bcol & 1023);
      ostride = 1024;
    } else {
      outp = (unsigned short*)Cout + bcol;
      ostride = (size_t)N;
    }
#pragma unroll
    for (int it = 0; it < BM / 16; it++) {
      const int fl = it * 4096 + tid * 8;    // u16 index into [BM][256]
      const int row = fl >> 8, colu = fl & 255;
      const int byo = row * 512 + ((colu * 2) ^ ((row & 7) << 4));
      const short8 val = *(const short8*)((char*)cst + byo);
      *(short8*)(outp + (size_t)(brow + row) * ostride + colu) = val;
    }
  } else {
    const int lc = lane & 15, lrow = (lane >> 4) * 4;
#pragma unroll
    for (int nf = 0; nf < 4; nf++) {
      const size_t col = bcol + wn * 64 + nf * 16 + lc;
      const float bv = bias[col];
#pragma unroll
      for (int mf = 0; mf < MF; mf++) {
#pragma unroll
        for (int j = 0; j < 4; j++) {
          const size_t row = brow + wm * WROWS + mf * 16 + lrow + j;
          const size_t idx = row * (size_t)N + col;
          ((float*)Cout)[idx] = acc[mf][nf][j] + bv + resid[idx];
        }
      }
    }
  }
}

// ---- 128x128 GEMM (kept for logits, N=128): +bias -> f32 ----------------
template <int EPI>
__global__ __launch_bounds__(256) void gemm_bf16(const unsigned short* __restrict__ A,
                                                 const unsigned short* __restrict__ BT,
                                                 const float* __restrict__ bias,
                                                 const float* __restrict__ resid,
                                                 void* __restrict__ Cout,
                                                 int M, int N, int K) {
  __shared__ unsigned short As[128 * 64];
  __shared__ unsigned short Bs[128 * 64];
  const int tid = threadIdx.x;
  const int lane = tid & 63, wid = tid >> 6;
  const int wr = wid >> 1, wc = wid & 1;
  const size_t brow = (size_t)blockIdx.y * 128;
  const size_t bcol = (size_t)blockIdx.x * 128;
  const unsigned short* Ab = A + brow * (size_t)K;
  const unsigned short* Bb = BT + bcol * (size_t)K;

  const f32x4 zero = {0.f, 0.f, 0.f, 0.f};
  f32x4 acc[4][4];
#pragma unroll
  for (int m = 0; m < 4; m++)
#pragma unroll
    for (int n = 0; n < 4; n++) acc[m][n] = zero;

  for (int k0 = 0; k0 < K; k0 += 64) {
#pragma unroll
    for (int i = 0; i < 4; i++) {
      const int eo = (i * 256 + tid) * 8;
      const int r = eo >> 6, c = eo & 63;
      async16(Ab + (size_t)r * K + (k0 + c), &As[eo]);
      async16(Bb + (size_t)r * K + (k0 + c), &Bs[eo]);
    }
    __syncthreads();
    const int lr = lane & 15, lk = (lane >> 4) * 8;
#pragma unroll
    for (int kk = 0; kk < 64; kk += 32) {
      short8 af[4], bfv[4];
#pragma unroll
      for (int m = 0; m < 4; m++)
        af[m] = *(const short8*)&As[(wr * 64 + m * 16 + lr) * 64 + kk + lk];
#pragma unroll
      for (int n = 0; n < 4; n++)
        bfv[n] = *(const short8*)&Bs[(wc * 64 + n * 16 + lr) * 64 + kk + lk];
#pragma unroll
      for (int m = 0; m < 4; m++)
#pragma unroll
        for (int n = 0; n < 4; n++)
          acc[m][n] = __builtin_amdgcn_mfma_f32_16x16x32_bf16(af[m], bfv[n], acc[m][n], 0, 0, 0);
    }
    __syncthreads();
  }

  const int lc = lane & 15, lr4 = (lane >> 4) * 4;
#pragma unroll
  for (int n = 0; n < 4; n++) {
    const size_t col = bcol + wc * 64 + n * 16 + lc;
    const float bv = bias[col];
#pragma unroll
    for (int m = 0; m < 4; m++) {
#pragma unroll
      for (int j = 0; j < 4; j++) {
        const size_t row = brow + wr * 64 + m * 16 + lr4 + j;
        const size_t idx = row * (size_t)N + col;
        ((float*)Cout)[idx] = acc[m][n][j] + bv;
      }
    }
  }
}

// ---- softmax over N for each (b,h); logits [M][128] f32, attn [B*H][N] --
__global__ __launch_bounds__(256) void softmax_k(const float* __restrict__ logits,
                                                 float* __restrict__ attn) {
  const int tid = threadIdx.x;
  const int bh = blockIdx.x;
  const int b = bh >> 4, h = bh & 15;
  __shared__ float redm[4];
  __shared__ float reds[4];
  float vals[4];
#pragma unroll
  for (int j = 0; j < 4; j++) {
    const int n = j * 256 + tid;
    vals[j] = logits[((size_t)b * 1024 + n) * 128 + h] * 0.125f;
  }
  float m = fmaxf(fmaxf(vals[0], vals[1]), fmaxf(vals[2], vals[3]));
#pragma unroll
  for (int o = 32; o > 0; o >>= 1) m = fmaxf(m, __shfl_xor(m, o));
  if ((tid & 63) == 0) redm[tid >> 6] = m;
  __syncthreads();
  m = fmaxf(fmaxf(redm[0], redm[1]), fmaxf(redm[2], redm[3]));
  float e[4];
  float s = 0.f;
#pragma unroll
  for (int j = 0; j < 4; j++) { e[j] = expf(vals[j] - m); s += e[j]; }
#pragma unroll
  for (int o = 32; o > 0; o >>= 1) s += __shfl_xor(s, o);
  if ((tid & 63) == 0) reds[tid >> 6] = s;
  __syncthreads();
  s = reds[0] + reds[1] + reds[2] + reds[3];
  const float invs = 1.f / s;
#pragma unroll
  for (int j = 0; j < 4; j++)
    attn[(size_t)bh * 1024 + j * 256 + tid] = e[j] * invs;
}

// ---- global_q[b,h,d] = sum_n attn[b,h,n] * Q[b,n,h*64+d] ----------------
__global__ __launch_bounds__(256) void global_q_k(const float* __restrict__ attn,
                                                  const unsigned short* __restrict__ Q,
                                                  float* __restrict__ gq) {
  const int tid = threadIdx.x;
  const int bh = blockIdx.x;
  const int b = bh >> 4, h = bh & 15;
  const int d = tid & 63, g = tid >> 6;
  const float* arow = attn + (size_t)bh * 1024;
  const unsigned short* qcol = Q + (size_t)b * 1024 * 1024 + h * 64 + d;
  float acc = 0.f;
  for (int n = g * 256; n < g * 256 + 256; n++)
    acc += arow[n] * bf2f(qcol[(size_t)n * 1024]);
  __shared__ float red[256];
  red[tid] = acc;
  __syncthreads();
  if (g == 0) gq[(size_t)bh * 64 + d] = red[d] + red[64 + d] + red[128 + d] + red[192 + d];
}

// ---- r = gq[b,h,d] * K * V (elementwise, bf16, in-place over K) ---------
__global__ __launch_bounds__(256) void r_k(const unsigned short* __restrict__ Kb,
                                           const unsigned short* __restrict__ Vb,
                                           const float* __restrict__ gq,
                                           unsigned short* __restrict__ R) {
  const size_t i = ((size_t)blockIdx.x * 256 + threadIdx.x) * 8;
  const int col = (int)(i & 1023);
  const size_t b = i >> 20;
  const int h = col >> 6, dd = col & 63;
  const float* g = gq + ((b << 4) + h) * 64 + dd;
  short8 kv = *(const short8*)(Kb + i);
  short8 vv = *(const short8*)(Vb + i);
  short8 r;
#pragma unroll
  for (int j = 0; j < 8; j++) {
    float f = g[j] * bf2f((unsigned short)kv[j]) * bf2f((unsigned short)vv[j]);
    r[j] = (short)f2bf(f);
  }
  *(short8*)(R + i) = r;
}

// ---------------------------------------------------------------------------
extern "C" void kernel_launch(void* const* d_in, const int* in_sizes, int n_in,
                              void* d_out, int out_size, void* d_ws, size_t ws_size,
                              hipStream_t stream) {
  (void)in_sizes; (void)n_in; (void)out_size; (void)ws_size;
  const float* inputs = (const float*)d_in[0];
  const float* z      = (const float*)d_in[1];
  const float* n1_hw = (const float*)d_in[2];  const float* n1_hb = (const float*)d_in[3];
  const float* n1_gw = (const float*)d_in[4];  const float* n1_gb = (const float*)d_in[5];
  const float* n1_bw = (const float*)d_in[6];  const float* n1_bb = (const float*)d_in[7];
  const float* wq_w  = (const float*)d_in[8];  const float* wq_b  = (const float*)d_in[9];
  const float* wk_w  = (const float*)d_in[10]; const float* wk_b  = (const float*)d_in[11];
  const float* wv_w  = (const float*)d_in[12]; const float* wv_b  = (const float*)d_in[13];
  const float* qa_w  = (const float*)d_in[14]; const float* qa_b  = (const float*)d_in[15];
  const float* out_w = (const float*)d_in[16]; const float* out_b = (const float*)d_in[17];
  const float* n2_hw = (const float*)d_in[18]; const float* n2_hb = (const float*)d_in[19];
  const float* n2_gw = (const float*)d_in[20]; const float* n2_gb = (const float*)d_in[21];
  const float* n2_bw = (const float*)d_in[22]; const float* n2_bb = (const float*)d_in[23];
  const float* mlp_w1 = (const float*)d_in[24]; const float* mlp_b1 = (const float*)d_in[25];
  const float* mlp_w2 = (const float*)d_in[26]; const float* mlp_b2 = (const float*)d_in[27];

  const int M = 8192, D = 1024, MLPD = 4096;

  char* ws = (char*)d_ws;
  size_t o = 0;
  auto alloc = [&](size_t bytes) -> char* {
    char* p = ws + o;
    o += (bytes + 255) & ~(size_t)255;
    return p;
  };
  unsigned short* wqkvT = (unsigned short*)alloc((size_t)3 * D * D * 2);  // [3072][1024]
  unsigned short* woT = (unsigned short*)alloc((size_t)D * D * 2);
  unsigned short* w1T = (unsigned short*)alloc((size_t)MLPD * D * 2);
  unsigned short* w2T = (unsigned short*)alloc((size_t)D * MLPD * 2);
  unsigned short* qaT = (unsigned short*)alloc((size_t)128 * D * 2);
  unsigned short* xn  = (unsigned short*)alloc((size_t)M * D * 2);
  char* big = alloc((size_t)M * MLPD * 2);  // 64MB: Q/K/V/logits early, hbuf late
  unsigned short* Qb = (unsigned short*)big;
  unsigned short* Kb = (unsigned short*)(big + (size_t)M * D * 2);
  unsigned short* Vb = (unsigned short*)(big + (size_t)M * D * 4);
  float* logits      = (float*)(big + (size_t)M * D * 6);  // [M][128] f32
  unsigned short* hbuf = (unsigned short*)big;             // [M][4096] bf16
  float* cacc  = (float*)alloc(6 * 8192 * 4);
  float* accH1 = cacc;
  float* accS1 = cacc + 1 * 8192;
  float* accT1 = cacc + 2 * 8192;
  float* accH2 = cacc + 3 * 8192;
  float* accS2 = cacc + 4 * 8192;
  float* accT2 = cacc + 5 * 8192;
  float* h1     = (float*)alloc(8 * 1024 * 4);
  float* h2     = (float*)alloc(8 * 1024 * 4);
  float* gq     = (float*)alloc(8 * 16 * 64 * 4);
  float* qa_b_pad = (float*)alloc(128 * 4);
  float* qkvb    = (float*)alloc(3072 * 4);

  float* out0 = (float*)d_out;                    // [M][D] final output / attn_out
  float* attn = (float*)d_out + (size_t)M * D;    // [B*H][N] attention maps

  const dim3 tb(32, 8);
  // weight transposes -> bf16 [N][K]; QKV concatenated into one [3072][1024]
  hipLaunchKernelGGL(transpose_bf16_k, dim3(32, 32), tb, 0, stream, wq_w, wqkvT, D, D);
  hipLaunchKernelGGL(transpose_bf16_k, dim3(32, 32), tb, 0, stream, wk_w, wqkvT + (size_t)D * D, D, D);
  hipLaunchKernelGGL(transpose_bf16_k, dim3(32, 32), tb, 0, stream, wv_w, wqkvT + (size_t)2 * D * D, D, D);
  hipLaunchKernelGGL(transpose_bf16_k, dim3(32, 32), tb, 0, stream, out_w, woT, D, D);
  hipLaunchKernelGGL(transpose_bf16_k, dim3(128, 32), tb, 0, stream, mlp_w1, w1T, D, MLPD);
  hipLaunchKernelGGL(transpose_bf16_k, dim3(32, 128), tb, 0, stream, mlp_w2, w2T, MLPD, D);
  hipLaunchKernelGGL(transpose_bf16_k, dim3(1, 32), tb, 0, stream, qa_w, qaT, D, 16);
  hipLaunchKernelGGL(pad_bias_k, dim3(1), dim3(128), 0, stream, qa_b, qa_b_pad);
  hipLaunchKernelGGL(bias3_k, dim3(12), dim3(256), 0, stream, wq_b, wk_b, wv_b, qkvb);

  // conditioning: zero accs, then K-split skinny GEMMs + epilogues
  hipLaunchKernelGGL(zero_k, dim3(48), dim3(256), 0, stream, (float4*)cacc);
  hipLaunchKernelGGL(skinny_k<1>, dim3(16, 16), dim3(256), 0, stream, z, n1_hw, (const float*)nullptr, accH1, (float*)nullptr);
  hipLaunchKernelGGL(h_epi_k, dim3(32), dim3(256), 0, stream, accH1, n1_hb, h1);
  hipLaunchKernelGGL(skinny_k<2>, dim3(16, 16), dim3(256), 0, stream, h1, n1_gw, n1_bw, accS1, accT1);
  hipLaunchKernelGGL(skinny_k<1>, dim3(16, 16), dim3(256), 0, stream, z, n2_hw, (const float*)nullptr, accH2, (float*)nullptr);
  hipLaunchKernelGGL(h_epi_k, dim3(32), dim3(256), 0, stream, accH2, n2_hb, h2);
  hipLaunchKernelGGL(skinny_k<2>, dim3(16, 16), dim3(256), 0, stream, h2, n2_gw, n2_bw, accS2, accT2);

  // LN1 -> xn (bf16)
  hipLaunchKernelGGL(ln_mod_k, dim3(M / 4), dim3(256), 0, stream, inputs, accS1, accT1, n1_gb, n1_bb, xn);

  // Q|K|V = xn @ wqkv (one N=3072 GEMM, epilogue splits into Qb/Kb/Vb)
  hipLaunchKernelGGL((gemm256<0, 256>), dim3(12, 32), dim3(512), 0, stream, xn, wqkvT, qkvb, (const float*)nullptr, (void*)Qb, M, 3072, D);

  // logits = Q @ qa_w + qa_b (padded to N=128)
  hipLaunchKernelGGL(gemm_bf16<3>, dim3(1, 64), dim3(256), 0, stream, Qb, qaT, qa_b_pad, (const float*)nullptr, (void*)logits, M, 128, D);

  // softmax -> attn maps (d_out region 1)
  hipLaunchKernelGGL(softmax_k, dim3(128), dim3(256), 0, stream, logits, attn);

  // global_q
  hipLaunchKernelGGL(global_q_k, dim3(128), dim3(256), 0, stream, attn, Qb, gq);

  // r = gq * K * V (in-place over K buffer)
  hipLaunchKernelGGL(r_k, dim3(M * D / 8 / 256), dim3(256), 0, stream, Kb, Vb, gq, Kb);

  // attn_out = inputs + r @ out_w + out_b  -> d_out region 0 (f32)
  hipLaunchKernelGGL((gemm256<2, 128>), dim3(4, 64), dim3(512), 0, stream, Kb, woT, out_b, inputs, (void*)out0, M, D, D);

  // LN2 -> xn (bf16)
  hipLaunchKernelGGL(ln_mod_k, dim3(M / 4), dim3(256), 0, stream, out0, accS2, accT2, n2_gb, n2_bb, xn);

  // MLP1 + exact gelu -> hbuf (bf16)
  hipLaunchKernelGGL((gemm256<1, 256>), dim3(16, 32), dim3(512), 0, stream, xn, w1T, mlp_b1, (const float*)nullptr, (void*)hbuf, M, MLPD, D);

  // MLP2 + attn_out residual -> final output (f32, in-place RMW on d_out)
  hipLaunchKernelGGL((gemm256<2, 128>), dim3(4, 64), dim3(512), 0, stream, hbuf, w2T, mlp_b2, out0, (void*)out0, M, D, MLPD);
}

// Round 10
// 647.407 us; speedup vs baseline: 1.0886x; 1.0313x over previous
//
#include <hip/hip_runtime.h>
#include <math.h>

// ---------------------------------------------------------------------------
// SMLadaformer block on MI355X. bf16 MFMA GEMMs, f32 elsewhere.
// B=8, N=1024, D=1024, H=16, DEPTH=64, MLP=4096. M = B*N = 8192.
// R4: conditioning matmuls K-split. R6: 256-tile dbuf pipeline + LDS swizzle.
// R8: coalesced bf16 epilogue (swapped-operand MFMA + LDS-staged stores):
//     WRITE 153->65MB verified. R9 profile: still stall-bound (MfmaUtil 17%,
//     2-phase barrier structure = ~72% overhead per m233) and XCD swizzle
//     regressed (L3-fit regime).
// R10: 4-phase-per-tile interleaved schedule (T3+T4): per phase {ds_read
//     quadrant ; stage 1 half-tile of t+1 ; 16 MFMA w/ setprio}; counted
//     vmcnt(2) only at tile boundary, never 0 mid-loop. XCD swizzle removed.
// ---------------------------------------------------------------------------

typedef __attribute__((ext_vector_type(8))) short short8;
typedef __attribute__((ext_vector_type(4))) float f32x4;

#define DEVI __device__ __forceinline__

DEVI unsigned short f2bf(float f) {
  union { float f; unsigned int u; } c; c.f = f;
  unsigned int r = c.u + 0x7fffu + ((c.u >> 16) & 1u);
  return (unsigned short)(r >> 16);
}
DEVI float bf2f(unsigned short u) {
  union { unsigned int u; float f; } c; c.u = ((unsigned int)u) << 16;
  return c.f;
}

DEVI void async16(const void* g, void* l) {
  __builtin_amdgcn_global_load_lds((const __attribute__((address_space(1))) void*)g,
                                   (__attribute__((address_space(3))) void*)l, 16, 0, 0);
}

// ---- transpose f32 [R][C] -> bf16 [C][R] --------------------------------
__global__ void transpose_bf16_k(const float* __restrict__ in,
                                 unsigned short* __restrict__ out, int R, int C) {
  __shared__ float tile[32][33];
  const int c0 = blockIdx.x * 32, r0 = blockIdx.y * 32;
  const int tx = threadIdx.x, ty = threadIdx.y;  // 32 x 8
#pragma unroll
  for (int j = 0; j < 4; j++) {
    int r = r0 + ty + j * 8, c = c0 + tx;
    if (r < R && c < C) tile[ty + j * 8][tx] = in[(size_t)r * C + c];
  }
  __syncthreads();
#pragma unroll
  for (int j = 0; j < 4; j++) {
    int c = c0 + ty + j * 8, r = r0 + tx;  // out[c][r]
    if (c < C && r < R) out[(size_t)c * R + r] = f2bf(tile[tx][ty + j * 8]);
  }
}

// ---- pad qa_b (16) -> 128 ------------------------------------------------
__global__ void pad_bias_k(const float* __restrict__ qa_b, float* __restrict__ pad) {
  int t = threadIdx.x;
  pad[t] = (t < 16) ? qa_b[t] : 0.f;
}

// ---- concat wq_b|wk_b|wv_b -> [3072] ------------------------------------
__global__ void bias3_k(const float* __restrict__ b0, const float* __restrict__ b1,
                        const float* __restrict__ b2, float* __restrict__ out) {
  const int t = blockIdx.x * 256 + threadIdx.x;  // 3072
  out[t] = (t < 1024) ? b0[t] : (t < 2048 ? b1[t - 1024] : b2[t - 2048]);
}

// ---- zero the conditioning accumulators (re-poison-safe init) -----------
__global__ void zero_k(float4* __restrict__ p) {
  p[blockIdx.x * 256 + threadIdx.x] = float4{0.f, 0.f, 0.f, 0.f};
}

// ---- skinny GEMM partial: acc[8][1024] += X[8,kchunk] @ W[kchunk,jtile] --
template <int NMAT>
__global__ __launch_bounds__(256) void skinny_k(const float* __restrict__ X,
                                                const float* __restrict__ W0,
                                                const float* __restrict__ W1,
                                                float* __restrict__ acc0,
                                                float* __restrict__ acc1) {
  const int tid = threadIdx.x;
  const int jt = blockIdx.x, kc = blockIdx.y;
  const int jl = tid & 63, kg = tid >> 6;
  const int jcol = jt * 64 + jl;
  __shared__ float xs[8][64];
  for (int i = tid; i < 512; i += 256) {
    const int b = i >> 6, kk = i & 63;
    xs[b][kk] = X[b * 1024 + kc * 64 + kk];
  }
  __syncthreads();
  float a0[8], a1[8];
#pragma unroll
  for (int b = 0; b < 8; b++) { a0[b] = 0.f; a1[b] = 0.f; }
#pragma unroll
  for (int kk = 0; kk < 16; kk++) {
    const int k = kg * 16 + kk;
    const float w0 = W0[(size_t)(kc * 64 + k) * 1024 + jcol];
#pragma unroll
    for (int b = 0; b < 8; b++) a0[b] += xs[b][k] * w0;
    if (NMAT == 2) {
      const float w1 = W1[(size_t)(kc * 64 + k) * 1024 + jcol];
#pragma unroll
      for (int b = 0; b < 8; b++) a1[b] += xs[b][k] * w1;
    }
  }
  __shared__ float red[256][9];
#pragma unroll
  for (int b = 0; b < 8; b++) red[tid][b] = a0[b];
  __syncthreads();
  if (tid < 64) {
#pragma unroll
    for (int b = 0; b < 8; b++) {
      const float s = red[tid][b] + red[tid + 64][b] + red[tid + 128][b] + red[tid + 192][b];
      atomicAdd(&acc0[b * 1024 + jcol], s);
    }
  }
  if (NMAT == 2) {
    __syncthreads();
#pragma unroll
    for (int b = 0; b < 8; b++) red[tid][b] = a1[b];
    __syncthreads();
    if (tid < 64) {
#pragma unroll
      for (int b = 0; b < 8; b++) {
        const float s = red[tid][b] + red[tid + 64][b] + red[tid + 128][b] + red[tid + 192][b];
        atomicAdd(&acc1[b * 1024 + jcol], s);
      }
    }
  }
}

// ---- h = relu(acc + hb) --------------------------------------------------
__global__ void h_epi_k(const float* __restrict__ acc, const float* __restrict__ hb,
                        float* __restrict__ h) {
  const int i = blockIdx.x * 256 + threadIdx.x;
  h[i] = fmaxf(acc[i] + hb[i & 1023], 0.f);
}

// ---- LayerNorm(last dim) * (s_acc+gb)[row] + (t_acc+bb)[row] -> bf16 ----
__global__ __launch_bounds__(256) void ln_mod_k(const float* __restrict__ x,
                                                const float* __restrict__ s_acc,
                                                const float* __restrict__ t_acc,
                                                const float* __restrict__ gb,
                                                const float* __restrict__ bb,
                                                unsigned short* __restrict__ out) {
  const int lane = threadIdx.x & 63, wid = threadIdx.x >> 6;
  const size_t row = (size_t)blockIdx.x * 4 + wid;
  const int n = (int)(row & 1023);
  const float4* xr = (const float4*)(x + row * 1024);
  float4 v[4];
  float s = 0.f, ss = 0.f;
#pragma unroll
  for (int j = 0; j < 4; j++) {
    v[j] = xr[j * 64 + lane];
    s += v[j].x + v[j].y + v[j].z + v[j].w;
    ss += v[j].x * v[j].x + v[j].y * v[j].y + v[j].z * v[j].z + v[j].w * v[j].w;
  }
#pragma unroll
  for (int o = 32; o > 0; o >>= 1) { s += __shfl_xor(s, o); ss += __shfl_xor(ss, o); }
  const float mean = s * (1.f / 1024.f);
  const float var = ss * (1.f / 1024.f) - mean * mean;
  const float inv = rsqrtf(var + 1e-6f);
  const float scale = s_acc[row] + gb[n];
  const float shift = t_acc[row] + bb[n];
  const float sc = scale * inv;
  const float sh = shift - mean * sc;
#pragma unroll
  for (int j = 0; j < 4; j++) {
    ushort4 o4;
    o4.x = f2bf(v[j].x * sc + sh);
    o4.y = f2bf(v[j].y * sc + sh);
    o4.z = f2bf(v[j].z * sc + sh);
    o4.w = f2bf(v[j].w * sc + sh);
    *(ushort4*)(out + row * 1024 + (size_t)(j * 64 + lane) * 4) = o4;
  }
}

// ---------------------------------------------------------------------------
// 256-col-tile GEMM, 8 waves (2M x 4N), BK=64, 4-phase-per-tile interleaved
// schedule: phase p computes C-quadrant p (16 MFMA) and stages one half-tile
// of t+1 into the dead buffer; vmcnt(2|1) + barrier only at tile boundary.
// LDS XOR-swizzle (granule g ^= row&7): linear gload dest + inverse-swizzled
// global src + swizzled ds_read (rule #21).
// EPI 0: QKV split (bf16, swapped-operand + coalesced LDS-staged stores)
// EPI 1: gelu -> bf16 (same store path)
// EPI 2: +resid -> f32 stride N
template <int EPI, int BM>
__global__ __launch_bounds__(512, 2) void gemm256(const unsigned short* __restrict__ A,
                                                  const unsigned short* __restrict__ BT,
                                                  const float* __restrict__ bias,
                                                  const float* __restrict__ resid,
                                                  void* __restrict__ Cout,
                                                  int M, int N, int K) {
  constexpr bool SWAP = (EPI == 0 || EPI == 1);
  constexpr int WROWS = BM / 2;              // per-wave output rows
  constexpr int MF = WROWS / 16;             // m-frags per wave (8 or 4)
  constexpr int MPH = MF / 2;                // m-frags per phase (4 or 2)
  constexpr int ALOADS_H = (WROWS * 64) / (512 * 8);  // A loads/thread/half: 2 or 1
  __shared__ unsigned short lds[2 * BM * 64 + 2 * 256 * 64];
  unsigned short* As0 = lds;                 // [2][BM*64]
  unsigned short* Bs0 = lds + 2 * BM * 64;   // [2][256*64]
  const int tid = threadIdx.x;
  const int lane = tid & 63, w = tid >> 6;
  const int wm = w >> 2, wn = w & 3;
  const int lr = lane & 15;
  const int g0 = lane >> 4;                  // k-granule of this lane per half
  const size_t brow = (size_t)blockIdx.y * BM;
  const size_t bcol = (size_t)blockIdx.x * 256;
  const unsigned short* Ab = A + brow * (size_t)K;
  const unsigned short* Bb = BT + bcol * (size_t)K;
  const int NT = K >> 6;

  const f32x4 zero = {0.f, 0.f, 0.f, 0.f};
  f32x4 acc[MF][4];
#pragma unroll
  for (int m = 0; m < MF; m++)
#pragma unroll
    for (int n = 0; n < 4; n++) acc[m][n] = zero;

  auto stageA = [&](int t, int h) {          // A rows [h*WROWS, (h+1)*WROWS)
    const int d = t & 1, k0 = t << 6;
#pragma unroll
    for (int i = 0; i < ALOADS_H; i++) {
      const int c = i * 512 + tid;
      const int r = h * WROWS + (c >> 3), g = c & 7;
      const int gl = g ^ (r & 7);
      async16(Ab + (size_t)r * K + (k0 + gl * 8),
              &As0[(size_t)d * BM * 64 + (size_t)h * WROWS * 64 + c * 8]);
    }
  };
  auto stageB = [&](int t, int h) {          // B rows [h*128, (h+1)*128)
    const int d = t & 1, k0 = t << 6;
#pragma unroll
    for (int i = 0; i < 2; i++) {
      const int c = i * 512 + tid;
      const int r = h * 128 + (c >> 3), g = c & 7;
      const int gl = g ^ (r & 7);
      async16(Bb + (size_t)r * K + (k0 + gl * 8),
              &Bs0[(size_t)d * 256 * 64 + (size_t)h * 128 * 64 + c * 8]);
    }
  };

  // prologue: all 4 halves of tile 0
  stageA(0, 0); stageA(0, 1); stageB(0, 0); stageB(0, 1);

  for (int t = 0; t < NT; ++t) {
    const unsigned short* as = As0 + (size_t)(t & 1) * BM * 64;
    const unsigned short* bs = Bs0 + (size_t)(t & 1) * 256 * 64;
#pragma unroll
    for (int p = 0; p < 4; ++p) {
      // stage one half-tile of t+1 into the dead buffer
      if (t + 1 < NT) {
        if (p == 0) stageA(t + 1, 0);
        else if (p == 1) stageA(t + 1, 1);
        else if (p == 2) stageB(t + 1, 0);
        else stageB(t + 1, 1);
      }
      if (p == 0) {  // tile-boundary gate: tile t resident, next-tile loads stay in flight
        if (t + 1 < NT) {
          if constexpr (ALOADS_H == 2) asm volatile("s_waitcnt vmcnt(2)" ::: "memory");
          else asm volatile("s_waitcnt vmcnt(1)" ::: "memory");
        } else {
          asm volatile("s_waitcnt vmcnt(0)" ::: "memory");
        }
        __builtin_amdgcn_s_barrier();
      }
      // ds_read quadrant p fragments
      const int mf0 = (p >> 1) * MPH;
      const int nf0 = (p & 1) * 2;
      short8 bfrag[2][2], afrag[2][MPH];
#pragma unroll
      for (int kki = 0; kki < 2; kki++) {
        const int gk = kki * 4 + g0;
#pragma unroll
        for (int nf = 0; nf < 2; nf++) {
          const int r = wn * 64 + (nf0 + nf) * 16 + lr;
          bfrag[kki][nf] = *(const short8*)&bs[r * 64 + ((gk ^ (r & 7)) << 3)];
        }
#pragma unroll
        for (int mf = 0; mf < MPH; mf++) {
          const int r = wm * WROWS + (mf0 + mf) * 16 + lr;
          afrag[kki][mf] = *(const short8*)&as[r * 64 + ((gk ^ (r & 7)) << 3)];
        }
      }
      __builtin_amdgcn_s_setprio(1);
#pragma unroll
      for (int kki = 0; kki < 2; kki++)
#pragma unroll
        for (int mf = 0; mf < MPH; mf++)
#pragma unroll
          for (int nf = 0; nf < 2; nf++) {
            if constexpr (SWAP)
              acc[mf0 + mf][nf0 + nf] = __builtin_amdgcn_mfma_f32_16x16x32_bf16(
                  bfrag[kki][nf], afrag[kki][mf], acc[mf0 + mf][nf0 + nf], 0, 0, 0);
            else
              acc[mf0 + mf][nf0 + nf] = __builtin_amdgcn_mfma_f32_16x16x32_bf16(
                  afrag[kki][mf], bfrag[kki][nf], acc[mf0 + mf][nf0 + nf], 0, 0, 0);
          }
      __builtin_amdgcn_s_setprio(0);
      __builtin_amdgcn_s_barrier();  // phase lockstep; p3's barrier guards tile boundary
    }
  }

  if constexpr (SWAP) {
    // acc is C^T-fragment: row = ...+lr, cols = ...+(lane>>4)*4+{0..3}.
    // Stage bf16 C tile [BM][256] in LDS (XOR bits 4-6 by row&7), then
    // stream out fully coalesced (512B contiguous per 32 lanes).
    unsigned short* cst = lds;
    const int g4 = (lane >> 4) * 4;
#pragma unroll
    for (int nf = 0; nf < 4; nf++) {
#pragma unroll
      for (int mf = 0; mf < MF; mf++) {
        const int row = wm * WROWS + mf * 16 + lr;
        const int colb = wn * 64 + nf * 16 + g4;
        const float4 bv = *(const float4*)&bias[bcol + colb];
        float v[4];
#pragma unroll
        for (int j = 0; j < 4; j++) {
          v[j] = acc[mf][nf][j] + (&bv.x)[j];
          if (EPI == 1) v[j] = 0.5f * v[j] * (1.0f + erff(v[j] * 0.70710678118654752f));
        }
        ushort4 pck;
        pck.x = f2bf(v[0]); pck.y = f2bf(v[1]); pck.z = f2bf(v[2]); pck.w = f2bf(v[3]);
        const int byo = row * 512 + ((colb * 2) ^ ((row & 7) << 4));
        *(ushort4*)((char*)cst + byo) = pck;
      }
    }
    __syncthreads();
    unsigned short* outp;
    size_t ostride;
    if (EPI == 0) {
      outp = (unsigned short*)Cout + (size_t)(bcol >> 10) * ((size_t)M << 10) + (bcol & 1023);
      ostride = 1024;
    } else {
      outp = (unsigned short*)Cout + bcol;
      ostride = (size_t)N;
    }
#pragma unroll
    for (int it = 0; it < BM / 16; it++) {
      const int fl = it * 4096 + tid * 8;    // u16 index into [BM][256]
      const int row = fl >> 8, colu = fl & 255;
      const int byo = row * 512 + ((colu * 2) ^ ((row & 7) << 4));
      const short8 val = *(const short8*)((char*)cst + byo);
      *(short8*)(outp + (size_t)(brow + row) * ostride + colu) = val;
    }
  } else {
    const int lc = lane & 15, lrow = (lane >> 4) * 4;
#pragma unroll
    for (int nf = 0; nf < 4; nf++) {
      const size_t col = bcol + wn * 64 + nf * 16 + lc;
      const float bv = bias[col];
#pragma unroll
      for (int mf = 0; mf < MF; mf++) {
#pragma unroll
        for (int j = 0; j < 4; j++) {
          const size_t row = brow + wm * WROWS + mf * 16 + lrow + j;
          const size_t idx = row * (size_t)N + col;
          ((float*)Cout)[idx] = acc[mf][nf][j] + bv + resid[idx];
        }
      }
    }
  }
}

// ---- 128x128 GEMM (kept for logits, N=128): +bias -> f32 ----------------
template <int EPI>
__global__ __launch_bounds__(256) void gemm_bf16(const unsigned short* __restrict__ A,
                                                 const unsigned short* __restrict__ BT,
                                                 const float* __restrict__ bias,
                                                 const float* __restrict__ resid,
                                                 void* __restrict__ Cout,
                                                 int M, int N, int K) {
  __shared__ unsigned short As[128 * 64];
  __shared__ unsigned short Bs[128 * 64];
  const int tid = threadIdx.x;
  const int lane = tid & 63, wid = tid >> 6;
  const int wr = wid >> 1, wc = wid & 1;
  const size_t brow = (size_t)blockIdx.y * 128;
  const size_t bcol = (size_t)blockIdx.x * 128;
  const unsigned short* Ab = A + brow * (size_t)K;
  const unsigned short* Bb = BT + bcol * (size_t)K;

  const f32x4 zero = {0.f, 0.f, 0.f, 0.f};
  f32x4 acc[4][4];
#pragma unroll
  for (int m = 0; m < 4; m++)
#pragma unroll
    for (int n = 0; n < 4; n++) acc[m][n] = zero;

  for (int k0 = 0; k0 < K; k0 += 64) {
#pragma unroll
    for (int i = 0; i < 4; i++) {
      const int eo = (i * 256 + tid) * 8;
      const int r = eo >> 6, c = eo & 63;
      async16(Ab + (size_t)r * K + (k0 + c), &As[eo]);
      async16(Bb + (size_t)r * K + (k0 + c), &Bs[eo]);
    }
    __syncthreads();
    const int lr = lane & 15, lk = (lane >> 4) * 8;
#pragma unroll
    for (int kk = 0; kk < 64; kk += 32) {
      short8 af[4], bfv[4];
#pragma unroll
      for (int m = 0; m < 4; m++)
        af[m] = *(const short8*)&As[(wr * 64 + m * 16 + lr) * 64 + kk + lk];
#pragma unroll
      for (int n = 0; n < 4; n++)
        bfv[n] = *(const short8*)&Bs[(wc * 64 + n * 16 + lr) * 64 + kk + lk];
#pragma unroll
      for (int m = 0; m < 4; m++)
#pragma unroll
        for (int n = 0; n < 4; n++)
          acc[m][n] = __builtin_amdgcn_mfma_f32_16x16x32_bf16(af[m], bfv[n], acc[m][n], 0, 0, 0);
    }
    __syncthreads();
  }

  const int lc = lane & 15, lr4 = (lane >> 4) * 4;
#pragma unroll
  for (int n = 0; n < 4; n++) {
    const size_t col = bcol + wc * 64 + n * 16 + lc;
    const float bv = bias[col];
#pragma unroll
    for (int m = 0; m < 4; m++) {
#pragma unroll
      for (int j = 0; j < 4; j++) {
        const size_t row = brow + wr * 64 + m * 16 + lr4 + j;
        const size_t idx = row * (size_t)N + col;
        ((float*)Cout)[idx] = acc[m][n][j] + bv;
      }
    }
  }
}

// ---- softmax over N for each (b,h); logits [M][128] f32, attn [B*H][N] --
__global__ __launch_bounds__(256) void softmax_k(const float* __restrict__ logits,
                                                 float* __restrict__ attn) {
  const int tid = threadIdx.x;
  const int bh = blockIdx.x;
  const int b = bh >> 4, h = bh & 15;
  __shared__ float redm[4];
  __shared__ float reds[4];
  float vals[4];
#pragma unroll
  for (int j = 0; j < 4; j++) {
    const int n = j * 256 + tid;
    vals[j] = logits[((size_t)b * 1024 + n) * 128 + h] * 0.125f;
  }
  float m = fmaxf(fmaxf(vals[0], vals[1]), fmaxf(vals[2], vals[3]));
#pragma unroll
  for (int o = 32; o > 0; o >>= 1) m = fmaxf(m, __shfl_xor(m, o));
  if ((tid & 63) == 0) redm[tid >> 6] = m;
  __syncthreads();
  m = fmaxf(fmaxf(redm[0], redm[1]), fmaxf(redm[2], redm[3]));
  float e[4];
  float s = 0.f;
#pragma unroll
  for (int j = 0; j < 4; j++) { e[j] = expf(vals[j] - m); s += e[j]; }
#pragma unroll
  for (int o = 32; o > 0; o >>= 1) s += __shfl_xor(s, o);
  if ((tid & 63) == 0) reds[tid >> 6] = s;
  __syncthreads();
  s = reds[0] + reds[1] + reds[2] + reds[3];
  const float invs = 1.f / s;
#pragma unroll
  for (int j = 0; j < 4; j++)
    attn[(size_t)bh * 1024 + j * 256 + tid] = e[j] * invs;
}

// ---- global_q[b,h,d] = sum_n attn[b,h,n] * Q[b,n,h*64+d] ----------------
__global__ __launch_bounds__(256) void global_q_k(const float* __restrict__ attn,
                                                  const unsigned short* __restrict__ Q,
                                                  float* __restrict__ gq) {
  const int tid = threadIdx.x;
  const int bh = blockIdx.x;
  const int b = bh >> 4, h = bh & 15;
  const int d = tid & 63, g = tid >> 6;
  const float* arow = attn + (size_t)bh * 1024;
  const unsigned short* qcol = Q + (size_t)b * 1024 * 1024 + h * 64 + d;
  float acc = 0.f;
  for (int n = g * 256; n < g * 256 + 256; n++)
    acc += arow[n] * bf2f(qcol[(size_t)n * 1024]);
  __shared__ float red[256];
  red[tid] = acc;
  __syncthreads();
  if (g == 0) gq[(size_t)bh * 64 + d] = red[d] + red[64 + d] + red[128 + d] + red[192 + d];
}

// ---- r = gq[b,h,d] * K * V (elementwise, bf16, in-place over K) ---------
__global__ __launch_bounds__(256) void r_k(const unsigned short* __restrict__ Kb,
                                           const unsigned short* __restrict__ Vb,
                                           const float* __restrict__ gq,
                                           unsigned short* __restrict__ R) {
  const size_t i = ((size_t)blockIdx.x * 256 + threadIdx.x) * 8;
  const int col = (int)(i & 1023);
  const size_t b = i >> 20;
  const int h = col >> 6, dd = col & 63;
  const float* g = gq + ((b << 4) + h) * 64 + dd;
  short8 kv = *(const short8*)(Kb + i);
  short8 vv = *(const short8*)(Vb + i);
  short8 r;
#pragma unroll
  for (int j = 0; j < 8; j++) {
    float f = g[j] * bf2f((unsigned short)kv[j]) * bf2f((unsigned short)vv[j]);
    r[j] = (short)f2bf(f);
  }
  *(short8*)(R + i) = r;
}

// ---------------------------------------------------------------------------
extern "C" void kernel_launch(void* const* d_in, const int* in_sizes, int n_in,
                              void* d_out, int out_size, void* d_ws, size_t ws_size,
                              hipStream_t stream) {
  (void)in_sizes; (void)n_in; (void)out_size; (void)ws_size;
  const float* inputs = (const float*)d_in[0];
  const float* z      = (const float*)d_in[1];
  const float* n1_hw = (const float*)d_in[2];  const float* n1_hb = (const float*)d_in[3];
  const float* n1_gw = (const float*)d_in[4];  const float* n1_gb = (const float*)d_in[5];
  const float* n1_bw = (const float*)d_in[6];  const float* n1_bb = (const float*)d_in[7];
  const float* wq_w  = (const float*)d_in[8];  const float* wq_b  = (const float*)d_in[9];
  const float* wk_w  = (const float*)d_in[10]; const float* wk_b  = (const float*)d_in[11];
  const float* wv_w  = (const float*)d_in[12]; const float* wv_b  = (const float*)d_in[13];
  const float* qa_w  = (const float*)d_in[14]; const float* qa_b  = (const float*)d_in[15];
  const float* out_w = (const float*)d_in[16]; const float* out_b = (const float*)d_in[17];
  const float* n2_hw = (const float*)d_in[18]; const float* n2_hb = (const float*)d_in[19];
  const float* n2_gw = (const float*)d_in[20]; const float* n2_gb = (const float*)d_in[21];
  const float* n2_bw = (const float*)d_in[22]; const float* n2_bb = (const float*)d_in[23];
  const float* mlp_w1 = (const float*)d_in[24]; const float* mlp_b1 = (const float*)d_in[25];
  const float* mlp_w2 = (const float*)d_in[26]; const float* mlp_b2 = (const float*)d_in[27];

  const int M = 8192, D = 1024, MLPD = 4096;

  char* ws = (char*)d_ws;
  size_t o = 0;
  auto alloc = [&](size_t bytes) -> char* {
    char* p = ws + o;
    o += (bytes + 255) & ~(size_t)255;
    return p;
  };
  unsigned short* wqkvT = (unsigned short*)alloc((size_t)3 * D * D * 2);  // [3072][1024]
  unsigned short* woT = (unsigned short*)alloc((size_t)D * D * 2);
  unsigned short* w1T = (unsigned short*)alloc((size_t)MLPD * D * 2);
  unsigned short* w2T = (unsigned short*)alloc((size_t)D * MLPD * 2);
  unsigned short* qaT = (unsigned short*)alloc((size_t)128 * D * 2);
  unsigned short* xn  = (unsigned short*)alloc((size_t)M * D * 2);
  char* big = alloc((size_t)M * MLPD * 2);  // 64MB: Q/K/V/logits early, hbuf late
  unsigned short* Qb = (unsigned short*)big;
  unsigned short* Kb = (unsigned short*)(big + (size_t)M * D * 2);
  unsigned short* Vb = (unsigned short*)(big + (size_t)M * D * 4);
  float* logits      = (float*)(big + (size_t)M * D * 6);  // [M][128] f32
  unsigned short* hbuf = (unsigned short*)big;             // [M][4096] bf16
  float* cacc  = (float*)alloc(6 * 8192 * 4);
  float* accH1 = cacc;
  float* accS1 = cacc + 1 * 8192;
  float* accT1 = cacc + 2 * 8192;
  float* accH2 = cacc + 3 * 8192;
  float* accS2 = cacc + 4 * 8192;
  float* accT2 = cacc + 5 * 8192;
  float* h1     = (float*)alloc(8 * 1024 * 4);
  float* h2     = (float*)alloc(8 * 1024 * 4);
  float* gq     = (float*)alloc(8 * 16 * 64 * 4);
  float* qa_b_pad = (float*)alloc(128 * 4);
  float* qkvb    = (float*)alloc(3072 * 4);

  float* out0 = (float*)d_out;                    // [M][D] final output / attn_out
  float* attn = (float*)d_out + (size_t)M * D;    // [B*H][N] attention maps

  const dim3 tb(32, 8);
  // weight transposes -> bf16 [N][K]; QKV concatenated into one [3072][1024]
  hipLaunchKernelGGL(transpose_bf16_k, dim3(32, 32), tb, 0, stream, wq_w, wqkvT, D, D);
  hipLaunchKernelGGL(transpose_bf16_k, dim3(32, 32), tb, 0, stream, wk_w, wqkvT + (size_t)D * D, D, D);
  hipLaunchKernelGGL(transpose_bf16_k, dim3(32, 32), tb, 0, stream, wv_w, wqkvT + (size_t)2 * D * D, D, D);
  hipLaunchKernelGGL(transpose_bf16_k, dim3(32, 32), tb, 0, stream, out_w, woT, D, D);
  hipLaunchKernelGGL(transpose_bf16_k, dim3(128, 32), tb, 0, stream, mlp_w1, w1T, D, MLPD);
  hipLaunchKernelGGL(transpose_bf16_k, dim3(32, 128), tb, 0, stream, mlp_w2, w2T, MLPD, D);
  hipLaunchKernelGGL(transpose_bf16_k, dim3(1, 32), tb, 0, stream, qa_w, qaT, D, 16);
  hipLaunchKernelGGL(pad_bias_k, dim3(1), dim3(128), 0, stream, qa_b, qa_b_pad);
  hipLaunchKernelGGL(bias3_k, dim3(12), dim3(256), 0, stream, wq_b, wk_b, wv_b, qkvb);

  // conditioning: zero accs, then K-split skinny GEMMs + epilogues
  hipLaunchKernelGGL(zero_k, dim3(48), dim3(256), 0, stream, (float4*)cacc);
  hipLaunchKernelGGL(skinny_k<1>, dim3(16, 16), dim3(256), 0, stream, z, n1_hw, (const float*)nullptr, accH1, (float*)nullptr);
  hipLaunchKernelGGL(h_epi_k, dim3(32), dim3(256), 0, stream, accH1, n1_hb, h1);
  hipLaunchKernelGGL(skinny_k<2>, dim3(16, 16), dim3(256), 0, stream, h1, n1_gw, n1_bw, accS1, accT1);
  hipLaunchKernelGGL(skinny_k<1>, dim3(16, 16), dim3(256), 0, stream, z, n2_hw, (const float*)nullptr, accH2, (float*)nullptr);
  hipLaunchKernelGGL(h_epi_k, dim3(32), dim3(256), 0, stream, accH2, n2_hb, h2);
  hipLaunchKernelGGL(skinny_k<2>, dim3(16, 16), dim3(256), 0, stream, h2, n2_gw, n2_bw, accS2, accT2);

  // LN1 -> xn (bf16)
  hipLaunchKernelGGL(ln_mod_k, dim3(M / 4), dim3(256), 0, stream, inputs, accS1, accT1, n1_gb, n1_bb, xn);

  // Q|K|V = xn @ wqkv (one N=3072 GEMM, epilogue splits into Qb/Kb/Vb)
  hipLaunchKernelGGL((gemm256<0, 256>), dim3(12, 32), dim3(512), 0, stream, xn, wqkvT, qkvb, (const float*)nullptr, (void*)Qb, M, 3072, D);

  // logits = Q @ qa_w + qa_b (padded to N=128)
  hipLaunchKernelGGL(gemm_bf16<3>, dim3(1, 64), dim3(256), 0, stream, Qb, qaT, qa_b_pad, (const float*)nullptr, (void*)logits, M, 128, D);

  // softmax -> attn maps (d_out region 1)
  hipLaunchKernelGGL(softmax_k, dim3(128), dim3(256), 0, stream, logits, attn);

  // global_q
  hipLaunchKernelGGL(global_q_k, dim3(128), dim3(256), 0, stream, attn, Qb, gq);

  // r = gq * K * V (in-place over K buffer)
  hipLaunchKernelGGL(r_k, dim3(M * D / 8 / 256), dim3(256), 0, stream, Kb, Vb, gq, Kb);

  // attn_out = inputs + r @ out_w + out_b  -> d_out region 0 (f32)
  hipLaunchKernelGGL((gemm256<2, 128>), dim3(4, 64), dim3(512), 0, stream, Kb, woT, out_b, inputs, (void*)out0, M, D, D);

  // LN2 -> xn (bf16)
  hipLaunchKernelGGL(ln_mod_k, dim3(M / 4), dim3(256), 0, stream, out0, accS2, accT2, n2_gb, n2_bb, xn);

  // MLP1 + exact gelu -> hbuf (bf16)
  hipLaunchKernelGGL((gemm256<1, 256>), dim3(16, 32), dim3(512), 0, stream, xn, w1T, mlp_b1, (const float*)nullptr, (void*)hbuf, M, MLPD, D);

  // MLP2 + attn_out residual -> final output (f32, in-place RMW on d_out)
  hipLaunchKernelGGL((gemm256<2, 128>), dim3(4, 64), dim3(512), 0, stream, hbuf, w2T, mlp_b2, out0, (void*)out0, M, D, MLPD);
}

// Round 12
// 635.863 us; speedup vs baseline: 1.1083x; 1.0182x over previous
//
#include <hip/hip_runtime.h>
#include <math.h>

// ---------------------------------------------------------------------------
// SMLadaformer block on MI355X. bf16 MFMA GEMMs, f32 elsewhere.
// B=8, N=1024, D=1024, H=16, DEPTH=64, MLP=4096. M = B*N = 8192.
// R4: conditioning K-split. R8: coalesced bf16 epilogue (WRITE 153->65MB).
// R10: 4-phase interleave: MLP1 164->103us but BM=128 kernels latency-bound
//      (1-tile-ahead coverage ~300cy < 900cy HBM latency; HBM eff 2TB/s).
// R11: uniform BM=128/BN=256/BK=64, THREE-buffer ring, 2-tiles-ahead
//      prefetch (gate vmcnt(6), never 0 mid-loop); 2 phases/tile.
//      Logits GEMM: K-split x4 + f32 atomicAdd (was 64-block grid).
// ---------------------------------------------------------------------------

typedef __attribute__((ext_vector_type(8))) short short8;
typedef __attribute__((ext_vector_type(4))) float f32x4;

#define DEVI __device__ __forceinline__

DEVI unsigned short f2bf(float f) {
  union { float f; unsigned int u; } c; c.f = f;
  unsigned int r = c.u + 0x7fffu + ((c.u >> 16) & 1u);
  return (unsigned short)(r >> 16);
}
DEVI float bf2f(unsigned short u) {
  union { unsigned int u; float f; } c; c.u = ((unsigned int)u) << 16;
  return c.f;
}

DEVI void async16(const void* g, void* l) {
  __builtin_amdgcn_global_load_lds((const __attribute__((address_space(1))) void*)g,
                                   (__attribute__((address_space(3))) void*)l, 16, 0, 0);
}

// ---- transpose f32 [R][C] -> bf16 [C][R] --------------------------------
__global__ void transpose_bf16_k(const float* __restrict__ in,
                                 unsigned short* __restrict__ out, int R, int C) {
  __shared__ float tile[32][33];
  const int c0 = blockIdx.x * 32, r0 = blockIdx.y * 32;
  const int tx = threadIdx.x, ty = threadIdx.y;  // 32 x 8
#pragma unroll
  for (int j = 0; j < 4; j++) {
    int r = r0 + ty + j * 8, c = c0 + tx;
    if (r < R && c < C) tile[ty + j * 8][tx] = in[(size_t)r * C + c];
  }
  __syncthreads();
#pragma unroll
  for (int j = 0; j < 4; j++) {
    int c = c0 + ty + j * 8, r = r0 + tx;  // out[c][r]
    if (c < C && r < R) out[(size_t)c * R + r] = f2bf(tile[tx][ty + j * 8]);
  }
}

// ---- pad qa_b (16) -> 128 ------------------------------------------------
__global__ void pad_bias_k(const float* __restrict__ qa_b, float* __restrict__ pad) {
  int t = threadIdx.x;
  pad[t] = (t < 16) ? qa_b[t] : 0.f;
}

// ---- concat wq_b|wk_b|wv_b -> [3072] ------------------------------------
__global__ void bias3_k(const float* __restrict__ b0, const float* __restrict__ b1,
                        const float* __restrict__ b2, float* __restrict__ out) {
  const int t = blockIdx.x * 256 + threadIdx.x;  // 3072
  out[t] = (t < 1024) ? b0[t] : (t < 2048 ? b1[t - 1024] : b2[t - 2048]);
}

// ---- zero f32 buffers (re-poison-safe init) -----------------------------
__global__ void zero_k(float4* __restrict__ p) {
  p[blockIdx.x * 256 + threadIdx.x] = float4{0.f, 0.f, 0.f, 0.f};
}

// ---- skinny GEMM partial: acc[8][1024] += X[8,kchunk] @ W[kchunk,jtile] --
template <int NMAT>
__global__ __launch_bounds__(256) void skinny_k(const float* __restrict__ X,
                                                const float* __restrict__ W0,
                                                const float* __restrict__ W1,
                                                float* __restrict__ acc0,
                                                float* __restrict__ acc1) {
  const int tid = threadIdx.x;
  const int jt = blockIdx.x, kc = blockIdx.y;
  const int jl = tid & 63, kg = tid >> 6;
  const int jcol = jt * 64 + jl;
  __shared__ float xs[8][64];
  for (int i = tid; i < 512; i += 256) {
    const int b = i >> 6, kk = i & 63;
    xs[b][kk] = X[b * 1024 + kc * 64 + kk];
  }
  __syncthreads();
  float a0[8], a1[8];
#pragma unroll
  for (int b = 0; b < 8; b++) { a0[b] = 0.f; a1[b] = 0.f; }
#pragma unroll
  for (int kk = 0; kk < 16; kk++) {
    const int k = kg * 16 + kk;
    const float w0 = W0[(size_t)(kc * 64 + k) * 1024 + jcol];
#pragma unroll
    for (int b = 0; b < 8; b++) a0[b] += xs[b][k] * w0;
    if (NMAT == 2) {
      const float w1 = W1[(size_t)(kc * 64 + k) * 1024 + jcol];
#pragma unroll
      for (int b = 0; b < 8; b++) a1[b] += xs[b][k] * w1;
    }
  }
  __shared__ float red[256][9];
#pragma unroll
  for (int b = 0; b < 8; b++) red[tid][b] = a0[b];
  __syncthreads();
  if (tid < 64) {
#pragma unroll
    for (int b = 0; b < 8; b++) {
      const float s = red[tid][b] + red[tid + 64][b] + red[tid + 128][b] + red[tid + 192][b];
      atomicAdd(&acc0[b * 1024 + jcol], s);
    }
  }
  if (NMAT == 2) {
    __syncthreads();
#pragma unroll
    for (int b = 0; b < 8; b++) red[tid][b] = a1[b];
    __syncthreads();
    if (tid < 64) {
#pragma unroll
      for (int b = 0; b < 8; b++) {
        const float s = red[tid][b] + red[tid + 64][b] + red[tid + 128][b] + red[tid + 192][b];
        atomicAdd(&acc1[b * 1024 + jcol], s);
      }
    }
  }
}

// ---- h = relu(acc + hb) --------------------------------------------------
__global__ void h_epi_k(const float* __restrict__ acc, const float* __restrict__ hb,
                        float* __restrict__ h) {
  const int i = blockIdx.x * 256 + threadIdx.x;
  h[i] = fmaxf(acc[i] + hb[i & 1023], 0.f);
}

// ---- LayerNorm(last dim) * (s_acc+gb)[row] + (t_acc+bb)[row] -> bf16 ----
__global__ __launch_bounds__(256) void ln_mod_k(const float* __restrict__ x,
                                                const float* __restrict__ s_acc,
                                                const float* __restrict__ t_acc,
                                                const float* __restrict__ gb,
                                                const float* __restrict__ bb,
                                                unsigned short* __restrict__ out) {
  const int lane = threadIdx.x & 63, wid = threadIdx.x >> 6;
  const size_t row = (size_t)blockIdx.x * 4 + wid;
  const int n = (int)(row & 1023);
  const float4* xr = (const float4*)(x + row * 1024);
  float4 v[4];
  float s = 0.f, ss = 0.f;
#pragma unroll
  for (int j = 0; j < 4; j++) {
    v[j] = xr[j * 64 + lane];
    s += v[j].x + v[j].y + v[j].z + v[j].w;
    ss += v[j].x * v[j].x + v[j].y * v[j].y + v[j].z * v[j].z + v[j].w * v[j].w;
  }
#pragma unroll
  for (int o = 32; o > 0; o >>= 1) { s += __shfl_xor(s, o); ss += __shfl_xor(ss, o); }
  const float mean = s * (1.f / 1024.f);
  const float var = ss * (1.f / 1024.f) - mean * mean;
  const float inv = rsqrtf(var + 1e-6f);
  const float scale = s_acc[row] + gb[n];
  const float shift = t_acc[row] + bb[n];
  const float sc = scale * inv;
  const float sh = shift - mean * sc;
#pragma unroll
  for (int j = 0; j < 4; j++) {
    ushort4 o4;
    o4.x = f2bf(v[j].x * sc + sh);
    o4.y = f2bf(v[j].y * sc + sh);
    o4.z = f2bf(v[j].z * sc + sh);
    o4.w = f2bf(v[j].w * sc + sh);
    *(ushort4*)(out + row * 1024 + (size_t)(j * 64 + lane) * 4) = o4;
  }
}

// ---------------------------------------------------------------------------
// BM=128 x BN=256 x BK=64 GEMM, 8 waves (2M x 4N), THREE-buffer ring with
// 2-tiles-ahead prefetch: tile t in buf[t%3]; loads for t issued during t-2;
// gate vmcnt(6) (t+1's 6 loads stay in flight), vmcnt(0) only at tail.
// 2 phases/tile (mf-split), 16 MFMA + 12 ds_read each, setprio-wrapped.
// LDS XOR-swizzle (granule g ^= row&7): linear gload dest + inverse-swizzled
// global src + swizzled ds_read (rule #21).
// EPI 0: QKV split (bf16, swapped-operand + coalesced LDS-staged stores)
// EPI 1: gelu -> bf16 (same store path)
// EPI 2: +resid -> f32 stride N
template <int EPI>
__global__ __launch_bounds__(512, 2) void gemm256(const unsigned short* __restrict__ A,
                                                  const unsigned short* __restrict__ BT,
                                                  const float* __restrict__ bias,
                                                  const float* __restrict__ resid,
                                                  void* __restrict__ Cout,
                                                  int M, int N, int K) {
  constexpr bool SWAP = (EPI == 0 || EPI == 1);
  constexpr int BUF = 128 * 64 + 256 * 64;   // u16 per buffer (A then B)
  __shared__ unsigned short lds[3 * BUF];    // 144 KiB
  const int tid = threadIdx.x;
  const int lane = tid & 63, w = tid >> 6;
  const int wm = w >> 2, wn = w & 3;
  const int lr = lane & 15;
  const int g0 = lane >> 4;                  // k-granule of this lane per half
  const size_t brow = (size_t)blockIdx.y * 128;
  const size_t bcol = (size_t)blockIdx.x * 256;
  const unsigned short* Ab = A + brow * (size_t)K;
  const unsigned short* Bb = BT + bcol * (size_t)K;
  const int NT = K >> 6;

  const f32x4 zero = {0.f, 0.f, 0.f, 0.f};
  f32x4 acc[4][4];
#pragma unroll
  for (int m = 0; m < 4; m++)
#pragma unroll
    for (int n = 0; n < 4; n++) acc[m][n] = zero;

  // stage half h (A rows [h*64,h*64+64), B rows [h*128,h*128+128)) of tile t
  auto stageH = [&](int t, int h) {
    const int bufo = (t % 3) * BUF;
    const int k0 = t << 6;
    {
      const int c = tid;
      const int r = h * 64 + (c >> 3), g = c & 7;
      const int gl = g ^ (r & 7);
      async16(Ab + (size_t)r * K + (k0 + gl * 8), &lds[bufo + h * 64 * 64 + c * 8]);
    }
#pragma unroll
    for (int i = 0; i < 2; i++) {
      const int c = i * 512 + tid;
      const int r = h * 128 + (c >> 3), g = c & 7;
      const int gl = g ^ (r & 7);
      async16(Bb + (size_t)r * K + (k0 + gl * 8),
              &lds[bufo + 128 * 64 + h * 128 * 64 + c * 8]);
    }
  };

  // prologue: tiles 0 and 1 fully staged (12 loads/thread)
  stageH(0, 0); stageH(0, 1); stageH(1, 0); stageH(1, 1);

  for (int t = 0; t < NT; ++t) {
    const unsigned short* as = &lds[(t % 3) * BUF];
    const unsigned short* bs = as + 128 * 64;
    // gate: tile t's 6 loads (issued during t-2) complete; t+1's stay in flight
    if (t + 1 < NT) asm volatile("s_waitcnt vmcnt(6)" ::: "memory");
    else asm volatile("s_waitcnt vmcnt(0)" ::: "memory");
    __builtin_amdgcn_s_barrier();
#pragma unroll
    for (int p = 0; p < 2; ++p) {
      if (t + 2 < NT) stageH(t + 2, p);   // prefetch into buf[(t+2)%3] (free)
      // ds_read: mf in {2p,2p+1}, all 4 nf, both k-halves
      short8 afrag[2][2], bfrag[2][4];
#pragma unroll
      for (int kki = 0; kki < 2; kki++) {
        const int gk = kki * 4 + g0;
#pragma unroll
        for (int m2 = 0; m2 < 2; m2++) {
          const int r = wm * 64 + (p * 2 + m2) * 16 + lr;
          afrag[kki][m2] = *(const short8*)&as[r * 64 + ((gk ^ (r & 7)) << 3)];
        }
#pragma unroll
        for (int nf = 0; nf < 4; nf++) {
          const int r = wn * 64 + nf * 16 + lr;
          bfrag[kki][nf] = *(const short8*)&bs[r * 64 + ((gk ^ (r & 7)) << 3)];
        }
      }
      __builtin_amdgcn_s_setprio(1);
#pragma unroll
      for (int kki = 0; kki < 2; kki++)
#pragma unroll
        for (int m2 = 0; m2 < 2; m2++)
#pragma unroll
          for (int nf = 0; nf < 4; nf++) {
            if constexpr (SWAP)
              acc[p * 2 + m2][nf] = __builtin_amdgcn_mfma_f32_16x16x32_bf16(
                  bfrag[kki][nf], afrag[kki][m2], acc[p * 2 + m2][nf], 0, 0, 0);
            else
              acc[p * 2 + m2][nf] = __builtin_amdgcn_mfma_f32_16x16x32_bf16(
                  afrag[kki][m2], bfrag[kki][nf], acc[p * 2 + m2][nf], 0, 0, 0);
          }
      __builtin_amdgcn_s_setprio(0);
      __builtin_amdgcn_s_barrier();       // phase lockstep
    }
  }

  if constexpr (SWAP) {
    // acc is C^T-fragment: row = ...+lr, cols = ...+(lane>>4)*4+{0..3}.
    // Stage bf16 C tile [128][256] in LDS (XOR bits 4-6 by row&7), then
    // stream out fully coalesced (512B contiguous per 32 lanes).
    unsigned short* cst = lds;  // 64 KiB needed
    const int g4 = (lane >> 4) * 4;
#pragma unroll
    for (int nf = 0; nf < 4; nf++) {
#pragma unroll
      for (int mf = 0; mf < 4; mf++) {
        const int row = wm * 64 + mf * 16 + lr;
        const int colb = wn * 64 + nf * 16 + g4;
        const float4 bv = *(const float4*)&bias[bcol + colb];
        float v[4];
#pragma unroll
        for (int j = 0; j < 4; j++) {
          v[j] = acc[mf][nf][j] + (&bv.x)[j];
          if (EPI == 1) v[j] = 0.5f * v[j] * (1.0f + erff(v[j] * 0.70710678118654752f));
        }
        ushort4 pck;
        pck.x = f2bf(v[0]); pck.y = f2bf(v[1]); pck.z = f2bf(v[2]); pck.w = f2bf(v[3]);
        const int byo = row * 512 + ((colb * 2) ^ ((row & 7) << 4));
        *(ushort4*)((char*)cst + byo) = pck;
      }
    }
    __syncthreads();
    unsigned short* outp;
    size_t ostride;
    if (EPI == 0) {
      outp = (unsigned short*)Cout + (size_t)(bcol >> 10) * ((size_t)M << 10) + (bcol & 1023);
      ostride = 1024;
    } else {
      outp = (unsigned short*)Cout + bcol;
      ostride = (size_t)N;
    }
#pragma unroll
    for (int it = 0; it < 8; it++) {
      const int fl = it * 4096 + tid * 8;    // u16 index into [128][256]
      const int row = fl >> 8, colu = fl & 255;
      const int byo = row * 512 + ((colu * 2) ^ ((row & 7) << 4));
      const short8 val = *(const short8*)((char*)cst + byo);
      *(short8*)(outp + (size_t)(brow + row) * ostride + colu) = val;
    }
  } else {
    const int lc = lane & 15, lrow = (lane >> 4) * 4;
#pragma unroll
    for (int nf = 0; nf < 4; nf++) {
      const size_t col = bcol + wn * 64 + nf * 16 + lc;
      const float bv = bias[col];
#pragma unroll
      for (int mf = 0; mf < 4; mf++) {
#pragma unroll
        for (int j = 0; j < 4; j++) {
          const size_t row = brow + wm * 64 + mf * 16 + lrow + j;
          const size_t idx = row * (size_t)N + col;
          ((float*)Cout)[idx] = acc[mf][nf][j] + bv + resid[idx];
        }
      }
    }
  }
}

// ---- logits GEMM, N=128, K-split x gridDim.x, f32 atomicAdd -------------
__global__ __launch_bounds__(256) void gemm_logits(const unsigned short* __restrict__ A,
                                                   const unsigned short* __restrict__ BT,
                                                   const float* __restrict__ bias,
                                                   float* __restrict__ out,
                                                   int M, int K) {
  __shared__ unsigned short As[128 * 64];
  __shared__ unsigned short Bs[128 * 64];
  const int tid = threadIdx.x;
  const int lane = tid & 63, wid = tid >> 6;
  const int wr = wid >> 1, wc = wid & 1;
  const int kc = blockIdx.x;
  const int KCH = K / gridDim.x;
  const size_t brow = (size_t)blockIdx.y * 128;
  const unsigned short* Ab = A + brow * (size_t)K;
  const unsigned short* Bb = BT;  // [128][K]

  const f32x4 zero = {0.f, 0.f, 0.f, 0.f};
  f32x4 acc[4][4];
#pragma unroll
  for (int m = 0; m < 4; m++)
#pragma unroll
    for (int n = 0; n < 4; n++) acc[m][n] = zero;

  for (int k0 = kc * KCH; k0 < (kc + 1) * KCH; k0 += 64) {
#pragma unroll
    for (int i = 0; i < 4; i++) {
      const int eo = (i * 256 + tid) * 8;
      const int r = eo >> 6, c = eo & 63;
      async16(Ab + (size_t)r * K + (k0 + c), &As[eo]);
      async16(Bb + (size_t)r * K + (k0 + c), &Bs[eo]);
    }
    __syncthreads();
    const int lr = lane & 15, lk = (lane >> 4) * 8;
#pragma unroll
    for (int kk = 0; kk < 64; kk += 32) {
      short8 af[4], bfv[4];
#pragma unroll
      for (int m = 0; m < 4; m++)
        af[m] = *(const short8*)&As[(wr * 64 + m * 16 + lr) * 64 + kk + lk];
#pragma unroll
      for (int n = 0; n < 4; n++)
        bfv[n] = *(const short8*)&Bs[(wc * 64 + n * 16 + lr) * 64 + kk + lk];
#pragma unroll
      for (int m = 0; m < 4; m++)
#pragma unroll
        for (int n = 0; n < 4; n++)
          acc[m][n] = __builtin_amdgcn_mfma_f32_16x16x32_bf16(af[m], bfv[n], acc[m][n], 0, 0, 0);
    }
    __syncthreads();
  }

  const int lc = lane & 15, lr4 = (lane >> 4) * 4;
#pragma unroll
  for (int n = 0; n < 4; n++) {
    const int col = wc * 64 + n * 16 + lc;
    const float bv = (kc == 0) ? bias[col] : 0.f;
#pragma unroll
    for (int m = 0; m < 4; m++) {
#pragma unroll
      for (int j = 0; j < 4; j++) {
        const size_t row = brow + wr * 64 + m * 16 + lr4 + j;
        atomicAdd(&out[row * 128 + col], acc[m][n][j] + bv);
      }
    }
  }
}

// ---- softmax over N for each (b,h); logits [M][128] f32, attn [B*H][N] --
__global__ __launch_bounds__(256) void softmax_k(const float* __restrict__ logits,
                                                 float* __restrict__ attn) {
  const int tid = threadIdx.x;
  const int bh = blockIdx.x;
  const int b = bh >> 4, h = bh & 15;
  __shared__ float redm[4];
  __shared__ float reds[4];
  float vals[4];
#pragma unroll
  for (int j = 0; j < 4; j++) {
    const int n = j * 256 + tid;
    vals[j] = logits[((size_t)b * 1024 + n) * 128 + h] * 0.125f;
  }
  float m = fmaxf(fmaxf(vals[0], vals[1]), fmaxf(vals[2], vals[3]));
#pragma unroll
  for (int o = 32; o > 0; o >>= 1) m = fmaxf(m, __shfl_xor(m, o));
  if ((tid & 63) == 0) redm[tid >> 6] = m;
  __syncthreads();
  m = fmaxf(fmaxf(redm[0], redm[1]), fmaxf(redm[2], redm[3]));
  float e[4];
  float s = 0.f;
#pragma unroll
  for (int j = 0; j < 4; j++) { e[j] = expf(vals[j] - m); s += e[j]; }
#pragma unroll
  for (int o = 32; o > 0; o >>= 1) s += __shfl_xor(s, o);
  if ((tid & 63) == 0) reds[tid >> 6] = s;
  __syncthreads();
  s = reds[0] + reds[1] + reds[2] + reds[3];
  const float invs = 1.f / s;
#pragma unroll
  for (int j = 0; j < 4; j++)
    attn[(size_t)bh * 1024 + j * 256 + tid] = e[j] * invs;
}

// ---- global_q[b,h,d] = sum_n attn[b,h,n] * Q[b,n,h*64+d] ----------------
__global__ __launch_bounds__(256) void global_q_k(const float* __restrict__ attn,
                                                  const unsigned short* __restrict__ Q,
                                                  float* __restrict__ gq) {
  const int tid = threadIdx.x;
  const int bh = blockIdx.x;
  const int b = bh >> 4, h = bh & 15;
  const int d = tid & 63, g = tid >> 6;
  const float* arow = attn + (size_t)bh * 1024;
  const unsigned short* qcol = Q + (size_t)b * 1024 * 1024 + h * 64 + d;
  float acc = 0.f;
  for (int n = g * 256; n < g * 256 + 256; n++)
    acc += arow[n] * bf2f(qcol[(size_t)n * 1024]);
  __shared__ float red[256];
  red[tid] = acc;
  __syncthreads();
  if (g == 0) gq[(size_t)bh * 64 + d] = red[d] + red[64 + d] + red[128 + d] + red[192 + d];
}

// ---- r = gq[b,h,d] * K * V (elementwise, bf16, in-place over K) ---------
__global__ __launch_bounds__(256) void r_k(const unsigned short* __restrict__ Kb,
                                           const unsigned short* __restrict__ Vb,
                                           const float* __restrict__ gq,
                                           unsigned short* __restrict__ R) {
  const size_t i = ((size_t)blockIdx.x * 256 + threadIdx.x) * 8;
  const int col = (int)(i & 1023);
  const size_t b = i >> 20;
  const int h = col >> 6, dd = col & 63;
  const float* g = gq + ((b << 4) + h) * 64 + dd;
  short8 kv = *(const short8*)(Kb + i);
  short8 vv = *(const short8*)(Vb + i);
  short8 r;
#pragma unroll
  for (int j = 0; j < 8; j++) {
    float f = g[j] * bf2f((unsigned short)kv[j]) * bf2f((unsigned short)vv[j]);
    r[j] = (short)f2bf(f);
  }
  *(short8*)(R + i) = r;
}

// ---------------------------------------------------------------------------
extern "C" void kernel_launch(void* const* d_in, const int* in_sizes, int n_in,
                              void* d_out, int out_size, void* d_ws, size_t ws_size,
                              hipStream_t stream) {
  (void)in_sizes; (void)n_in; (void)out_size; (void)ws_size;
  const float* inputs = (const float*)d_in[0];
  const float* z      = (const float*)d_in[1];
  const float* n1_hw = (const float*)d_in[2];  const float* n1_hb = (const float*)d_in[3];
  const float* n1_gw = (const float*)d_in[4];  const float* n1_gb = (const float*)d_in[5];
  const float* n1_bw = (const float*)d_in[6];  const float* n1_bb = (const float*)d_in[7];
  const float* wq_w  = (const float*)d_in[8];  const float* wq_b  = (const float*)d_in[9];
  const float* wk_w  = (const float*)d_in[10]; const float* wk_b  = (const float*)d_in[11];
  const float* wv_w  = (const float*)d_in[12]; const float* wv_b  = (const float*)d_in[13];
  const float* qa_w  = (const float*)d_in[14]; const float* qa_b  = (const float*)d_in[15];
  const float* out_w = (const float*)d_in[16]; const float* out_b = (const float*)d_in[17];
  const float* n2_hw = (const float*)d_in[18]; const float* n2_hb = (const float*)d_in[19];
  const float* n2_gw = (const float*)d_in[20]; const float* n2_gb = (const float*)d_in[21];
  const float* n2_bw = (const float*)d_in[22]; const float* n2_bb = (const float*)d_in[23];
  const float* mlp_w1 = (const float*)d_in[24]; const float* mlp_b1 = (const float*)d_in[25];
  const float* mlp_w2 = (const float*)d_in[26]; const float* mlp_b2 = (const float*)d_in[27];

  const int M = 8192, D = 1024, MLPD = 4096;

  char* ws = (char*)d_ws;
  size_t o = 0;
  auto alloc = [&](size_t bytes) -> char* {
    char* p = ws + o;
    o += (bytes + 255) & ~(size_t)255;
    return p;
  };
  unsigned short* wqkvT = (unsigned short*)alloc((size_t)3 * D * D * 2);  // [3072][1024]
  unsigned short* woT = (unsigned short*)alloc((size_t)D * D * 2);
  unsigned short* w1T = (unsigned short*)alloc((size_t)MLPD * D * 2);
  unsigned short* w2T = (unsigned short*)alloc((size_t)D * MLPD * 2);
  unsigned short* qaT = (unsigned short*)alloc((size_t)128 * D * 2);
  unsigned short* xn  = (unsigned short*)alloc((size_t)M * D * 2);
  char* big = alloc((size_t)M * MLPD * 2);  // 64MB: Q/K/V/logits early, hbuf late
  unsigned short* Qb = (unsigned short*)big;
  unsigned short* Kb = (unsigned short*)(big + (size_t)M * D * 2);
  unsigned short* Vb = (unsigned short*)(big + (size_t)M * D * 4);
  float* logits      = (float*)(big + (size_t)M * D * 6);  // [M][128] f32 (4MB)
  unsigned short* hbuf = (unsigned short*)big;             // [M][4096] bf16
  float* cacc  = (float*)alloc(6 * 8192 * 4);
  float* accH1 = cacc;
  float* accS1 = cacc + 1 * 8192;
  float* accT1 = cacc + 2 * 8192;
  float* accH2 = cacc + 3 * 8192;
  float* accS2 = cacc + 4 * 8192;
  float* accT2 = cacc + 5 * 8192;
  float* h1     = (float*)alloc(8 * 1024 * 4);
  float* h2     = (float*)alloc(8 * 1024 * 4);
  float* gq     = (float*)alloc(8 * 16 * 64 * 4);
  float* qa_b_pad = (float*)alloc(128 * 4);
  float* qkvb    = (float*)alloc(3072 * 4);

  float* out0 = (float*)d_out;                    // [M][D] final output / attn_out
  float* attn = (float*)d_out + (size_t)M * D;    // [B*H][N] attention maps

  const dim3 tb(32, 8);
  // weight transposes -> bf16 [N][K]; QKV concatenated into one [3072][1024]
  hipLaunchKernelGGL(transpose_bf16_k, dim3(32, 32), tb, 0, stream, wq_w, wqkvT, D, D);
  hipLaunchKernelGGL(transpose_bf16_k, dim3(32, 32), tb, 0, stream, wk_w, wqkvT + (size_t)D * D, D, D);
  hipLaunchKernelGGL(transpose_bf16_k, dim3(32, 32), tb, 0, stream, wv_w, wqkvT + (size_t)2 * D * D, D, D);
  hipLaunchKernelGGL(transpose_bf16_k, dim3(32, 32), tb, 0, stream, out_w, woT, D, D);
  hipLaunchKernelGGL(transpose_bf16_k, dim3(128, 32), tb, 0, stream, mlp_w1, w1T, D, MLPD);
  hipLaunchKernelGGL(transpose_bf16_k, dim3(32, 128), tb, 0, stream, mlp_w2, w2T, MLPD, D);
  hipLaunchKernelGGL(transpose_bf16_k, dim3(1, 32), tb, 0, stream, qa_w, qaT, D, 16);
  hipLaunchKernelGGL(pad_bias_k, dim3(1), dim3(128), 0, stream, qa_b, qa_b_pad);
  hipLaunchKernelGGL(bias3_k, dim3(12), dim3(256), 0, stream, wq_b, wk_b, wv_b, qkvb);

  // zero conditioning accs (196KB) and logits (4MB)
  hipLaunchKernelGGL(zero_k, dim3(48), dim3(256), 0, stream, (float4*)cacc);
  hipLaunchKernelGGL(zero_k, dim3(1024), dim3(256), 0, stream, (float4*)logits);

  // conditioning: K-split skinny GEMMs + epilogues
  hipLaunchKernelGGL(skinny_k<1>, dim3(16, 16), dim3(256), 0, stream, z, n1_hw, (const float*)nullptr, accH1, (float*)nullptr);
  hipLaunchKernelGGL(h_epi_k, dim3(32), dim3(256), 0, stream, accH1, n1_hb, h1);
  hipLaunchKernelGGL(skinny_k<2>, dim3(16, 16), dim3(256), 0, stream, h1, n1_gw, n1_bw, accS1, accT1);
  hipLaunchKernelGGL(skinny_k<1>, dim3(16, 16), dim3(256), 0, stream, z, n2_hw, (const float*)nullptr, accH2, (float*)nullptr);
  hipLaunchKernelGGL(h_epi_k, dim3(32), dim3(256), 0, stream, accH2, n2_hb, h2);
  hipLaunchKernelGGL(skinny_k<2>, dim3(16, 16), dim3(256), 0, stream, h2, n2_gw, n2_bw, accS2, accT2);

  // LN1 -> xn (bf16)
  hipLaunchKernelGGL(ln_mod_k, dim3(M / 4), dim3(256), 0, stream, inputs, accS1, accT1, n1_gb, n1_bb, xn);

  // Q|K|V = xn @ wqkv (one N=3072 GEMM, epilogue splits into Qb/Kb/Vb)
  hipLaunchKernelGGL(gemm256<0>, dim3(12, 64), dim3(512), 0, stream, xn, wqkvT, qkvb, (const float*)nullptr, (void*)Qb, M, 3072, D);

  // logits = Q @ qa_w + qa_b (K-split x4, atomicAdd into zeroed buffer)
  hipLaunchKernelGGL(gemm_logits, dim3(4, 64), dim3(256), 0, stream, Qb, qaT, qa_b_pad, logits, M, D);

  // softmax -> attn maps (d_out region 1)
  hipLaunchKernelGGL(softmax_k, dim3(128), dim3(256), 0, stream, logits, attn);

  // global_q
  hipLaunchKernelGGL(global_q_k, dim3(128), dim3(256), 0, stream, attn, Qb, gq);

  // r = gq * K * V (in-place over K buffer)
  hipLaunchKernelGGL(r_k, dim3(M * D / 8 / 256), dim3(256), 0, stream, Kb, Vb, gq, Kb);

  // attn_out = inputs + r @ out_w + out_b  -> d_out region 0 (f32)
  hipLaunchKernelGGL(gemm256<2>, dim3(4, 64), dim3(512), 0, stream, Kb, woT, out_b, inputs, (void*)out0, M, D, D);

  // LN2 -> xn (bf16)
  hipLaunchKernelGGL(ln_mod_k, dim3(M / 4), dim3(256), 0, stream, out0, accS2, accT2, n2_gb, n2_bb, xn);

  // MLP1 + exact gelu -> hbuf (bf16)
  hipLaunchKernelGGL(gemm256<1>, dim3(16, 64), dim3(512), 0, stream, xn, w1T, mlp_b1, (const float*)nullptr, (void*)hbuf, M, MLPD, D);

  // MLP2 + attn_out residual -> final output (f32, in-place RMW on d_out)
  hipLaunchKernelGGL(gemm256<2>, dim3(4, 64), dim3(512), 0, stream, hbuf, w2T, mlp_b2, out0, (void*)out0, M, D, MLPD);
}